// Round 6
// baseline (623.318 us; speedup 1.0000x reference)
//
#include <hip/hip_runtime.h>
#include <hip/hip_bf16.h>
#include <hip/hip_cooperative_groups.h>

namespace cg = cooperative_groups;

#define NND 2048
#define BBATCH 4
#define SS 1024
#define SFZ 384
#define IFZ 256
#define HH 8
#define AA 64
#define HA 512
#define ABLK 6    // 128-node x-blocks per batch (768-node capacity, 13 sigma)
#define NGRP 8    // 16-node groups per x-block
#define NSPL 8    // S-splits in attention
#define GRID_BLKS 512   // 2 blocks/CU on 256 CUs -> cooperative co-residency

typedef __attribute__((ext_vector_type(8))) short bf16x8;
typedef __attribute__((ext_vector_type(4))) float f32x4;
typedef __attribute__((ext_vector_type(2))) unsigned int u32x2;

__device__ __forceinline__ unsigned short f2bf(float f) {
    union { float f; unsigned u; } a; a.f = f;
    unsigned r = a.u + 0x7fffu + ((a.u >> 16) & 1u);
    return (unsigned short)(r >> 16);
}
__device__ __forceinline__ float bf2f(unsigned short u) {
    return __uint_as_float((unsigned)u << 16);
}

__device__ __forceinline__ bf16x8 cvt8(const float* __restrict__ p) {
    const float4 f0 = *(const float4*)p;
    const float4 f1 = *(const float4*)(p + 4);
    bf16x8 o;
    o[0] = (short)f2bf(f0.x); o[1] = (short)f2bf(f0.y);
    o[2] = (short)f2bf(f0.z); o[3] = (short)f2bf(f0.w);
    o[4] = (short)f2bf(f1.x); o[5] = (short)f2bf(f1.y);
    o[6] = (short)f2bf(f1.z); o[7] = (short)f2bf(f1.w);
    return o;
}

// --- forced-issue async loads (asm volatile preserves issue order) ---
__device__ __forceinline__ bf16x8 gld16(const unsigned short* p) {
    bf16x8 r;
    asm volatile("global_load_dwordx4 %0, %1, off" : "=&v"(r) : "v"(p));
    return r;
}
__device__ __forceinline__ f32x4 gldf4(const float* p) {
    f32x4 r;
    asm volatile("global_load_dwordx4 %0, %1, off" : "=&v"(r) : "v"(p));
    return r;
}
__device__ __forceinline__ u32x2 gld8(const unsigned short* p) {
    u32x2 r;
    asm volatile("global_load_dwordx2 %0, %1, off" : "=&v"(r) : "v"(p));
    return r;
}
__device__ __forceinline__ float gldf(const float* p) {
    float r;
    asm volatile("global_load_dword %0, %1, off" : "=&v"(r) : "v"(p));
    return r;
}
#define VMWAIT0() do { \
    asm volatile("s_waitcnt vmcnt(0)" ::: "memory"); \
    __builtin_amdgcn_sched_barrier(0); \
} while (0)

// ---------------------------------------------------------------------------
// Phase 1: prep (weight transposes + mask/batch decode). Valid for bx < 193.
// ---------------------------------------------------------------------------
__device__ __forceinline__ void tile_transpose(
    const float* __restrict__ src, unsigned short* __restrict__ dst,
    unsigned short (*tile)[65], int K, int N, int kt, int nt, int t)
{
    const int k0 = kt * 64, n0 = nt * 64;
    const int tr = t >> 6, tc = t & 63;
    #pragma unroll
    for (int r = 0; r < 16; ++r)
        tile[tr + r*4][tc] = f2bf(src[(size_t)(k0 + tr + r*4) * N + n0 + tc]);
    __syncthreads();
    #pragma unroll
    for (int r = 0; r < 16; ++r)
        dst[(size_t)(n0 + tr + r*4) * K + k0 + tc] = tile[tc][tr + r*4];
}

__device__ __forceinline__ void phase_prep(
    int bx, int t, char* smem,
    const float* __restrict__ Wk, const float* __restrict__ Wv,
    const float* __restrict__ Wq, const float* __restrict__ Wg,
    const float* __restrict__ Wback,
    const void* __restrict__ mraw, const void* __restrict__ braw,
    unsigned short* __restrict__ WkT, unsigned short* __restrict__ WvT,
    unsigned short* __restrict__ WqT, unsigned short* __restrict__ WgT,
    unsigned short* __restrict__ WbackT,
    float* __restrict__ mask_f, int* __restrict__ seg)
{
    if (bx >= 193) return;
    if (bx < 192) {
        unsigned short (*tile)[65] = (unsigned short (*)[65])smem;
        if (bx < 48)       tile_transpose(Wk, WkT, tile, SFZ, HA, bx/8, bx%8, t);
        else if (bx < 96)  { const int i = bx-48;  tile_transpose(Wv, WvT, tile, SFZ, HA, i/8, i%8, t); }
        else if (bx < 128) { const int i = bx-96;  tile_transpose(Wq, WqT, tile, IFZ, HA, i/8, i%8, t); }
        else if (bx < 160) { const int i = bx-128; tile_transpose(Wg, WgT, tile, IFZ, HA, i/8, i%8, t); }
        else               { const int i = bx-160; tile_transpose(Wback, WbackT, tile, HA, IFZ, i/4, i%4, t); }
        return;
    }
    int* fl  = (int*)(smem);
    int* fbp = (int*)(smem + 16);
    int* cnt = (int*)(smem + 32);
    if (t < 4) { fl[t] = 0; cnt[t] = 0; }
    if (t == 0) *fbp = 0;
    __syncthreads();
    const unsigned char*  mb = (const unsigned char*)mraw;
    const unsigned short* mh = (const unsigned short*)mraw;
    const unsigned int*   mw = (const unsigned int*)mraw;
    int f0 = 0, f1 = 0, f2 = 0, f3 = 0;
    for (int i = t; i < 2048; i += 256) {
        unsigned short hh = mh[i];
        if (hh == 0x3f80u) f0 = 1;
        if ((i & 1) == 0 && hh != 0) f1 = 1;
    }
    for (int i = t; i < 4096; i += 256)
        if ((i & 3) != 0 && mb[i] != 0) f2 = 1;
    for (int i = t; i < 1024; i += 256)
        if ((i & 1) != 0 && mw[i] != 0) f3 = 1;
    const int* bw = (const int*)braw;
    int f4 = 0;
    for (int i = t + 1; i < 2048; i += 256)
        if (bw[i] < bw[i-1]) f4 = 1;
    if (f0) atomicOr(&fl[0], 1);
    if (f1) atomicOr(&fl[1], 1);
    if (f2) atomicOr(&fl[2], 1);
    if (f3) atomicOr(&fl[3], 1);
    if (f4) atomicOr(fbp, 1);
    __syncthreads();
    int mode;
    if (fl[0])      mode = fl[1] ? 1 : 0;
    else if (fl[2]) mode = 2;
    else if (fl[3]) mode = 3;
    else            mode = 4;
    for (int s = t; s < BBATCH*SS; s += 256) {
        int m;
        switch (mode) {
            case 0:  m = (mw[s]   != 0); break;
            case 1:  m = (mh[s]   != 0); break;
            case 2:  m = (mb[s]   != 0); break;
            case 3:  m = (mw[s]   != 0); break;
            default: m = (mw[2*s] != 0); break;
        }
        mask_f[s] = m ? 1.0f : 0.0f;
    }
    const int b64 = *fbp;
    for (int i = t; i < NND; i += 256) {
        const int bv = (b64 ? bw[2*i] : bw[i]) & 3;
        atomicAdd(&cnt[bv], 1);
    }
    __syncthreads();
    if (t == 0) {
        int s = 0;
        for (int b = 0; b < 4; ++b) { seg[2*b] = s; s += cnt[b]; seg[2*b+1] = s; }
    }
}

// ---------------------------------------------------------------------------
// Phase 2: fused MFMA projections. Valid for bx < 512.
// ---------------------------------------------------------------------------
__device__ __forceinline__ void phase_proj(
    int bx, int t, char* smem,
    const float* __restrict__ emb, const float* __restrict__ x,
    const unsigned short* __restrict__ WkT, const unsigned short* __restrict__ WvT,
    const unsigned short* __restrict__ WqT, const unsigned short* __restrict__ WgT,
    const float* __restrict__ bg,
    unsigned short* __restrict__ k_blk, unsigned short* __restrict__ vT_bf,
    unsigned short* __restrict__ q_bf, float* __restrict__ gate_ws)
{
    const int w = t >> 6, lane = t & 63;
    const int m16 = lane & 15, quad = lane >> 4;
    unsigned short (*v_l)[520] = (unsigned short (*)[520])smem;  // 16.6 KB
    if (bx < 256) {
        const int r0 = bx * 16;
        const int b = r0 >> 10, srow = r0 & (SS - 1);
        const float* ap = emb + (size_t)(r0 + m16) * SFZ + quad * 8;
        bf16x8 af[12];
        #pragma unroll
        for (int j = 0; j < 12; ++j) af[j] = cvt8(ap + j * 32);
        #pragma unroll
        for (int tensor = 0; tensor < 2; ++tensor) {
            const unsigned short* Wt = tensor ? WvT : WkT;
            #pragma unroll
            for (int g = 0; g < 2; ++g) {
                const int n0g = w * 128 + g * 64;
                const unsigned short* bp0 = Wt + (size_t)(n0g +  0 + m16) * SFZ + quad * 8;
                const unsigned short* bp1 = Wt + (size_t)(n0g + 16 + m16) * SFZ + quad * 8;
                const unsigned short* bp2 = Wt + (size_t)(n0g + 32 + m16) * SFZ + quad * 8;
                const unsigned short* bp3 = Wt + (size_t)(n0g + 48 + m16) * SFZ + quad * 8;
                f32x4 a0 = (f32x4){0.f, 0.f, 0.f, 0.f};
                f32x4 a1 = a0, a2 = a0, a3 = a0;
                bf16x8 wb[24];
                #pragma unroll
                for (int j = 0; j < 6; ++j) {
                    wb[j*4+0] = gld16(bp0 + j * 32);
                    wb[j*4+1] = gld16(bp1 + j * 32);
                    wb[j*4+2] = gld16(bp2 + j * 32);
                    wb[j*4+3] = gld16(bp3 + j * 32);
                }
                VMWAIT0();
                #pragma unroll
                for (int j = 0; j < 6; ++j) {
                    a0 = __builtin_amdgcn_mfma_f32_16x16x32_bf16(af[j], wb[j*4+0], a0, 0, 0, 0);
                    a1 = __builtin_amdgcn_mfma_f32_16x16x32_bf16(af[j], wb[j*4+1], a1, 0, 0, 0);
                    a2 = __builtin_amdgcn_mfma_f32_16x16x32_bf16(af[j], wb[j*4+2], a2, 0, 0, 0);
                    a3 = __builtin_amdgcn_mfma_f32_16x16x32_bf16(af[j], wb[j*4+3], a3, 0, 0, 0);
                }
                #pragma unroll
                for (int j = 6; j < 12; ++j) {
                    wb[(j-6)*4+0] = gld16(bp0 + j * 32);
                    wb[(j-6)*4+1] = gld16(bp1 + j * 32);
                    wb[(j-6)*4+2] = gld16(bp2 + j * 32);
                    wb[(j-6)*4+3] = gld16(bp3 + j * 32);
                }
                VMWAIT0();
                #pragma unroll
                for (int j = 6; j < 12; ++j) {
                    a0 = __builtin_amdgcn_mfma_f32_16x16x32_bf16(af[j], wb[(j-6)*4+0], a0, 0, 0, 0);
                    a1 = __builtin_amdgcn_mfma_f32_16x16x32_bf16(af[j], wb[(j-6)*4+1], a1, 0, 0, 0);
                    a2 = __builtin_amdgcn_mfma_f32_16x16x32_bf16(af[j], wb[(j-6)*4+2], a2, 0, 0, 0);
                    a3 = __builtin_amdgcn_mfma_f32_16x16x32_bf16(af[j], wb[(j-6)*4+3], a3, 0, 0, 0);
                }
                f32x4 dd[4] = {a0, a1, a2, a3};
                if (tensor == 0) {
                    #pragma unroll
                    for (int u = 0; u < 4; ++u) {
                        const int n0 = n0g + u * 16;
                        const int head = n0 >> 6, coff = (n0 & 63) + m16;
                        unsigned short* kb = k_blk + (((size_t)(b * HH + head)) * SS) * 64 + coff;
                        #pragma unroll
                        for (int r = 0; r < 4; ++r)
                            kb[(size_t)(srow + quad * 4 + r) * 64] = f2bf(dd[u][r]);
                    }
                } else {
                    #pragma unroll
                    for (int u = 0; u < 4; ++u) {
                        const int c0 = n0g + u * 16 + m16;
                        #pragma unroll
                        for (int r = 0; r < 4; ++r)
                            v_l[quad * 4 + r][c0] = f2bf(dd[u][r]);
                    }
                }
            }
        }
        __syncthreads();
        for (int c = t; c < HA; c += 256) {
            unsigned short tmp[16];
            #pragma unroll
            for (int s = 0; s < 16; ++s) tmp[s] = v_l[s][c];
            unsigned short* dst = vT_bf + ((size_t)b * HA + c) * SS + srow;
            *(uint4*)dst       = ((const uint4*)tmp)[0];
            *(uint4*)(dst + 8) = ((const uint4*)tmp)[1];
        }
    } else if (bx < 512) {
        const int i = bx - 256;
        const int r0 = (i >> 1) * 16;
        const int half = i & 1;
        const float* ap = x + (size_t)(r0 + m16) * IFZ + quad * 8;
        bf16x8 af[8];
        #pragma unroll
        for (int j = 0; j < 8; ++j) af[j] = cvt8(ap + j * 32);
        const int n0b = half * 256 + w * 64;
        #pragma unroll
        for (int tensor = 0; tensor < 2; ++tensor) {
            const unsigned short* Wt = tensor ? WgT : WqT;
            const unsigned short* bp0 = Wt + (size_t)(n0b +  0 + m16) * IFZ + quad * 8;
            const unsigned short* bp1 = Wt + (size_t)(n0b + 16 + m16) * IFZ + quad * 8;
            const unsigned short* bp2 = Wt + (size_t)(n0b + 32 + m16) * IFZ + quad * 8;
            const unsigned short* bp3 = Wt + (size_t)(n0b + 48 + m16) * IFZ + quad * 8;
            bf16x8 wb[32];
            #pragma unroll
            for (int j = 0; j < 8; ++j) {
                wb[j*4+0] = gld16(bp0 + j * 32);
                wb[j*4+1] = gld16(bp1 + j * 32);
                wb[j*4+2] = gld16(bp2 + j * 32);
                wb[j*4+3] = gld16(bp3 + j * 32);
            }
            VMWAIT0();
            f32x4 a0 = (f32x4){0.f, 0.f, 0.f, 0.f};
            f32x4 a1 = a0, a2 = a0, a3 = a0;
            #pragma unroll
            for (int j = 0; j < 8; ++j) {
                a0 = __builtin_amdgcn_mfma_f32_16x16x32_bf16(af[j], wb[j*4+0], a0, 0, 0, 0);
                a1 = __builtin_amdgcn_mfma_f32_16x16x32_bf16(af[j], wb[j*4+1], a1, 0, 0, 0);
                a2 = __builtin_amdgcn_mfma_f32_16x16x32_bf16(af[j], wb[j*4+2], a2, 0, 0, 0);
                a3 = __builtin_amdgcn_mfma_f32_16x16x32_bf16(af[j], wb[j*4+3], a3, 0, 0, 0);
            }
            f32x4 dd[4] = {a0, a1, a2, a3};
            if (tensor == 0) {
                #pragma unroll
                for (int u = 0; u < 4; ++u) {
                    const int n0 = n0b + u * 16;
                    #pragma unroll
                    for (int r = 0; r < 4; ++r)
                        q_bf[(size_t)(r0 + quad * 4 + r) * HA + n0 + m16] = f2bf(dd[u][r]);
                }
            } else {
                #pragma unroll
                for (int u = 0; u < 4; ++u) {
                    const int n0 = n0b + u * 16;
                    const float bgv = bg[n0 + m16];
                    #pragma unroll
                    for (int r = 0; r < 4; ++r)
                        gate_ws[(size_t)(r0 + quad * 4 + r) * HA + n0 + m16] =
                            1.f / (1.f + __expf(-(dd[u][r] + bgv)));
                }
            }
        }
    }
}

// ---------------------------------------------------------------------------
// Phase 3: flash attention + fused logits (K/V reuse). Valid for bx < 384.
// ---------------------------------------------------------------------------
__device__ __forceinline__ void phase_attn(
    int bx, int t, char* smem,
    const unsigned short* __restrict__ k_blk, const unsigned short* __restrict__ vT_bf,
    const unsigned short* __restrict__ q_bf, const float* __restrict__ mask_f,
    const int* __restrict__ seg, unsigned short* __restrict__ part_O,
    float2* __restrict__ part_ml, float* __restrict__ out_logits)
{
    if (bx >= BBATCH * ABLK * 16) return;
    unsigned short (*P_lds)[16][136] = (unsigned short (*)[16][136])smem;     // 17.4 KB
    float (*raw0)[16][132] = (float (*)[16][132])(smem + 17408);              // 16.9 KB
    const int xcd = bx & 7;
    const int b   = xcd >> 1;
    const int idx = (bx >> 3) * 2 + (xcd & 1);   // [0,96)
    const int z    = idx & 15;
    const int xblk = idx >> 4;                   // [0,6)
    const int hz    = z >> 3;
    const int split = z & 7;
    const int nbase = seg[2*b] + xblk * (16 * NGRP);
    const int nend  = seg[2*b + 1];
    if (nbase >= nend) return;

    const int w = t >> 6, lane = t & 63;
    const int m16 = lane & 15, quad = lane >> 4;
    const int h = hz * 4 + w;
    const int s0 = split * 128;
    const unsigned short* kb = k_blk + ((size_t)(b * HH + h)) * SS * 64;
    const unsigned short* vb = vT_bf + ((size_t)b * HA + h * AA) * SS;
    const unsigned short* qbase = q_bf + (size_t)h * AA + quad * 8;
    unsigned short (*Pw)[136] = P_lds[w];

    bf16x8 kf[16];
    #pragma unroll
    for (int st = 0; st < 8; ++st) {
        const unsigned short* kp = kb + (size_t)(s0 + st * 16 + m16) * 64 + quad * 8;
        kf[2*st]   = gld16(kp);
        kf[2*st+1] = gld16(kp + 32);
    }
    bf16x8 vf[16];
    #pragma unroll
    for (int sub = 0; sub < 4; ++sub) {
        const unsigned short* vp0 = vb + (size_t)m16 * SS + s0 + sub * 32 + quad * 8;
        #pragma unroll
        for (int a = 0; a < 4; ++a)
            vf[sub*4+a] = gld16(vp0 + (size_t)(a * 16) * SS);
    }
    float msk[8];
    #pragma unroll
    for (int st = 0; st < 8; ++st)
        msk[st] = gldf(mask_f + b * SS + s0 + st * 16 + m16);
    int nq0 = nbase + m16; if (nq0 >= nend) nq0 = nend - 1;
    bf16x8 qc0 = gld16(qbase + (size_t)nq0 * HA);
    bf16x8 qc1 = gld16(qbase + (size_t)nq0 * HA + 32);
    VMWAIT0();

    bf16x8 qn0 = qc0, qn1 = qc1;
    for (int g = 0; g < NGRP; ++g) {
        const int n0g = nbase + g * 16;
        if (n0g >= nend) break;
        if (g > 0) {
            VMWAIT0();
            qc0 = qn0; qc1 = qn1;
        }
        const int nvalid = min(16, nend - n0g);

        f32x4 d[8];
        #pragma unroll
        for (int st = 0; st < 8; ++st) {
            f32x4 acc = (f32x4){0.f, 0.f, 0.f, 0.f};
            acc = __builtin_amdgcn_mfma_f32_16x16x32_bf16(qc0, kf[2*st],   acc, 0, 0, 0);
            acc = __builtin_amdgcn_mfma_f32_16x16x32_bf16(qc1, kf[2*st+1], acc, 0, 0, 0);
            #pragma unroll
            for (int r = 0; r < 4; ++r) acc[r] *= 0.125f;
            d[st] = acc;
        }
        if (g + 1 < NGRP && nbase + (g + 1) * 16 < nend) {
            int nqn = nbase + (g + 1) * 16 + m16; if (nqn >= nend) nqn = nend - 1;
            qn0 = gld16(qbase + (size_t)nqn * HA);
            qn1 = gld16(qbase + (size_t)nqn * HA + 32);
        }
        __builtin_amdgcn_sched_barrier(0);

        if (hz == 0) {
            if (w == 0) {
                #pragma unroll
                for (int st = 0; st < 8; ++st)
                    #pragma unroll
                    for (int r = 0; r < 4; ++r)
                        raw0[g & 1][quad * 4 + r][st * 16 + m16] = d[st][r];
            }
            __syncthreads();
            if (w == 1) {
                #pragma unroll
                for (int st = 0; st < 8; ++st)
                    #pragma unroll
                    for (int r = 0; r < 4; ++r) {
                        const int row = quad * 4 + r;
                        if (row < nvalid)
                            out_logits[(size_t)(n0g + row) * SS + s0 + st * 16 + m16] =
                                raw0[g & 1][row][st * 16 + m16] + d[st][r];
                    }
            }
        }
        float m_s[4], l_s[4];
        #pragma unroll
        for (int r = 0; r < 4; ++r) {
            float mx = -3.0e38f;
            #pragma unroll
            for (int st = 0; st < 8; ++st)
                mx = (msk[st] > 0.5f) ? fmaxf(mx, d[st][r]) : mx;
            mx = fmaxf(mx, __shfl_xor(mx, 1));
            mx = fmaxf(mx, __shfl_xor(mx, 2));
            mx = fmaxf(mx, __shfl_xor(mx, 4));
            mx = fmaxf(mx, __shfl_xor(mx, 8));
            m_s[r] = mx;
            float cs = 0.f;
            #pragma unroll
            for (int st = 0; st < 8; ++st) {
                const float e = (msk[st] > 0.5f) ? __expf(d[st][r] - mx) : 0.f;
                d[st][r] = e;
                cs += e;
            }
            cs += __shfl_xor(cs, 1);
            cs += __shfl_xor(cs, 2);
            cs += __shfl_xor(cs, 4);
            cs += __shfl_xor(cs, 8);
            l_s[r] = cs;
        }
        #pragma unroll
        for (int st = 0; st < 8; ++st)
            #pragma unroll
            for (int r = 0; r < 4; ++r)
                Pw[quad * 4 + r][st * 16 + m16] = f2bf(d[st][r]);
        bf16x8 pa[4];
        #pragma unroll
        for (int sub = 0; sub < 4; ++sub)
            pa[sub] = *(const bf16x8*)&Pw[m16][sub * 32 + quad * 8];
        f32x4 facc[4];
        #pragma unroll
        for (int a = 0; a < 4; ++a) facc[a] = (f32x4){0.f, 0.f, 0.f, 0.f};
        #pragma unroll
        for (int sub = 0; sub < 4; ++sub) {
            #pragma unroll
            for (int a = 0; a < 4; ++a)
                facc[a] = __builtin_amdgcn_mfma_f32_16x16x32_bf16(pa[sub], vf[sub*4+a], facc[a], 0, 0, 0);
        }
        unsigned short* po = part_O + (size_t)split * NND * HA;
        #pragma unroll
        for (int a = 0; a < 4; ++a)
            #pragma unroll
            for (int r = 0; r < 4; ++r) {
                const int row = quad * 4 + r;
                if (row < nvalid)
                    po[(size_t)(n0g + row) * HA + h * AA + a * 16 + m16] = f2bf(facc[a][r]);
            }
        if (m16 == 0) {
            #pragma unroll
            for (int r = 0; r < 4; ++r) {
                const int row = quad * 4 + r;
                if (row < nvalid)
                    part_ml[(size_t)split * NND * HH + (size_t)(n0g + row) * HH + h] =
                        make_float2(m_s[r], l_s[r]);
            }
        }
    }
}

// ---------------------------------------------------------------------------
// Phase 4: combine + gate + Wback MFMA + residual + LN. Valid for bx < 256.
// ---------------------------------------------------------------------------
__device__ __forceinline__ void phase_back(
    int bx, int t, char* smem,
    const unsigned short* __restrict__ part_O, const float2* __restrict__ part_ml,
    const float* __restrict__ gate_ws, const unsigned short* __restrict__ WbackT,
    const float* __restrict__ x, const float* __restrict__ bback,
    const float* __restrict__ gamma, const float* __restrict__ beta,
    float* __restrict__ out)
{
    if (bx >= NND / 8) return;
    float (*coef)[8][8] = (float (*)[8][8])smem;                               // 2 KB
    unsigned short (*gf_l)[520] = (unsigned short (*)[520])(smem + 2048);      // 8.3 KB
    float (*nl)[260] = (float (*)[260])(smem + 2048 + 8320);                   // 8.3 KB
    const int w = t >> 6, lane = t & 63;
    const int m16 = lane & 15, quad = lane >> 4;
    const int r0 = bx * 8;
    if (t < 64) {
        const int row = t >> 3, h = t & 7, n = r0 + row;
        float2 ml[NSPL];
        #pragma unroll
        for (int s = 0; s < NSPL; ++s)
            ml[s] = part_ml[(size_t)s * NND * HH + (size_t)n * HH + h];
        float M = -3.0e38f;
        #pragma unroll
        for (int s = 0; s < NSPL; ++s) M = fmaxf(M, ml[s].x);
        float L = 0.f;
        float e[NSPL];
        #pragma unroll
        for (int s = 0; s < NSPL; ++s) { e[s] = __expf(ml[s].x - M); L += ml[s].y * e[s]; }
        const float invL = 1.f / (L + 1e-9f);
        #pragma unroll
        for (int s = 0; s < NSPL; ++s) coef[s][row][h] = e[s] * invL;
    }
    u32x2 pvv[4][NSPL];
    f32x4 gv[4];
    #pragma unroll
    for (int it = 0; it < 4; ++it) {
        const int i = (t + it * 256) * 4;
        const int row = i >> 9, c = i & (HA - 1);
        const int n = r0 + row;
        #pragma unroll
        for (int s = 0; s < NSPL; ++s)
            pvv[it][s] = gld8(&part_O[(size_t)s * NND * HA + (size_t)n * HA + c]);
        gv[it] = gldf4(&gate_ws[(size_t)n * HA + c]);
    }
    __syncthreads();
    VMWAIT0();
    #pragma unroll
    for (int it = 0; it < 4; ++it) {
        const int i = (t + it * 256) * 4;
        const int row = i >> 9, c = i & (HA - 1), h = c >> 6;
        float4 o = make_float4(0.f, 0.f, 0.f, 0.f);
        #pragma unroll
        for (int s = 0; s < NSPL; ++s) {
            const float cf = coef[s][row][h];
            o.x = fmaf(bf2f((unsigned short)(pvv[it][s][0] & 0xffffu)), cf, o.x);
            o.y = fmaf(bf2f((unsigned short)(pvv[it][s][0] >> 16)),     cf, o.y);
            o.z = fmaf(bf2f((unsigned short)(pvv[it][s][1] & 0xffffu)), cf, o.z);
            o.w = fmaf(bf2f((unsigned short)(pvv[it][s][1] >> 16)),     cf, o.w);
        }
        ushort4 ob;
        ob.x = f2bf(gv[it][0] * o.x); ob.y = f2bf(gv[it][1] * o.y);
        ob.z = f2bf(gv[it][2] * o.z); ob.w = f2bf(gv[it][3] * o.w);
        *(ushort4*)&gf_l[row][c] = ob;
    }
    __syncthreads();
    bf16x8 af[16];
    #pragma unroll
    for (int j = 0; j < 16; ++j)
        af[j] = *(const bf16x8*)&gf_l[m16 & 7][quad * 8 + j * 32];
    const unsigned short* bq0 = WbackT + (size_t)(w * 64 +  0 + m16) * HA + quad * 8;
    const unsigned short* bq1 = WbackT + (size_t)(w * 64 + 16 + m16) * HA + quad * 8;
    const unsigned short* bq2 = WbackT + (size_t)(w * 64 + 32 + m16) * HA + quad * 8;
    const unsigned short* bq3 = WbackT + (size_t)(w * 64 + 48 + m16) * HA + quad * 8;
    f32x4 a0 = (f32x4){0.f, 0.f, 0.f, 0.f};
    f32x4 a1 = a0, a2 = a0, a3 = a0;
    #pragma unroll
    for (int jb = 0; jb < 4; ++jb) {
        bf16x8 wb[16];
        #pragma unroll
        for (int j = 0; j < 4; ++j) {
            wb[j*4+0] = gld16(bq0 + (jb*4 + j) * 32);
            wb[j*4+1] = gld16(bq1 + (jb*4 + j) * 32);
            wb[j*4+2] = gld16(bq2 + (jb*4 + j) * 32);
            wb[j*4+3] = gld16(bq3 + (jb*4 + j) * 32);
        }
        VMWAIT0();
        #pragma unroll
        for (int j = 0; j < 4; ++j) {
            a0 = __builtin_amdgcn_mfma_f32_16x16x32_bf16(af[jb*4+j], wb[j*4+0], a0, 0, 0, 0);
            a1 = __builtin_amdgcn_mfma_f32_16x16x32_bf16(af[jb*4+j], wb[j*4+1], a1, 0, 0, 0);
            a2 = __builtin_amdgcn_mfma_f32_16x16x32_bf16(af[jb*4+j], wb[j*4+2], a2, 0, 0, 0);
            a3 = __builtin_amdgcn_mfma_f32_16x16x32_bf16(af[jb*4+j], wb[j*4+3], a3, 0, 0, 0);
        }
    }
    {
        f32x4 dd[4] = {a0, a1, a2, a3};
        #pragma unroll
        for (int u = 0; u < 4; ++u) {
            const int n0 = w * 64 + u * 16;
            const float bb = bback[n0 + m16];
            #pragma unroll
            for (int r = 0; r < 4; ++r) {
                const int rr = quad * 4 + r;
                if (rr < 8) nl[rr][n0 + m16] = dd[u][r] + bb;
            }
        }
    }
    __syncthreads();
    const int row = t >> 5, li = t & 31;
    const float* xr = x + (size_t)(r0 + row) * IFZ;
    float yv[8];
    float s1 = 0.f, s2 = 0.f;
    #pragma unroll
    for (int j = 0; j < 8; ++j) {
        const int c = li + j * 32;
        const float v = fmaf(1.41421356237309515f, xr[c], nl[row][c]);
        yv[j] = v; s1 += v; s2 += v * v;
    }
    #pragma unroll
    for (int off = 16; off >= 1; off >>= 1) {
        s1 += __shfl_xor(s1, off);
        s2 += __shfl_xor(s2, off);
    }
    const float mu  = s1 * (1.f / IFZ);
    const float var = s2 * (1.f / IFZ) - mu * mu;
    const float rv  = rsqrtf(var + 1e-5f);
    float* orow = out + (size_t)(r0 + row) * IFZ;
    #pragma unroll
    for (int j = 0; j < 8; ++j) {
        const int c = li + j * 32;
        orow[c] = (yv[j] - mu) * rv * gamma[c] + beta[c];
    }
}

// ---------------------------------------------------------------------------
// Cooperative fused kernel: grid.sync is only an EXECUTION barrier with
// workgroup-scope fences; per-XCD L2s are NOT coherent. __threadfence()
// (agent scope: buffer_wbl2/buffer_inv sc1) before AND after each sync makes
// cross-phase data visible through the coherent point (IF$).
// ---------------------------------------------------------------------------
__global__ __launch_bounds__(256, 2) void fused_all(
    const float* __restrict__ emb, const float* __restrict__ x,
    const float* __restrict__ Wk, const float* __restrict__ Wv,
    const float* __restrict__ Wq, const float* __restrict__ Wg,
    const float* __restrict__ Wback,
    const void* __restrict__ mraw, const void* __restrict__ braw,
    const float* __restrict__ bg, const float* __restrict__ bback,
    const float* __restrict__ gamma, const float* __restrict__ beta,
    unsigned short* __restrict__ WkT, unsigned short* __restrict__ WvT,
    unsigned short* __restrict__ WqT, unsigned short* __restrict__ WgT,
    unsigned short* __restrict__ WbackT,
    float* __restrict__ mask_f, int* __restrict__ seg,
    unsigned short* __restrict__ k_blk, unsigned short* __restrict__ vT_bf,
    unsigned short* __restrict__ q_bf, float* __restrict__ gate_ws,
    unsigned short* __restrict__ part_O, float2* __restrict__ part_ml,
    float* __restrict__ out, float* __restrict__ out_logits)
{
    __shared__ __align__(16) char smem[34304];
    cg::grid_group grid = cg::this_grid();
    const int bx = blockIdx.x;
    const int t = threadIdx.x;

    phase_prep(bx, t, smem, Wk, Wv, Wq, Wg, Wback, mraw, braw,
               WkT, WvT, WqT, WgT, WbackT, mask_f, seg);
    __threadfence(); grid.sync(); __threadfence();

    phase_proj(bx, t, smem, emb, x, WkT, WvT, WqT, WgT, bg,
               k_blk, vT_bf, q_bf, gate_ws);
    __threadfence(); grid.sync(); __threadfence();

    phase_attn(bx, t, smem, k_blk, vT_bf, q_bf, mask_f, seg,
               part_O, part_ml, out_logits);
    __threadfence(); grid.sync(); __threadfence();

    phase_back(bx, t, smem, part_O, part_ml, gate_ws, WbackT, x,
               bback, gamma, beta, out);
}

// ---------------------------------------------------------------------------
// Fallback standalone kernels (identical bodies; kernel boundaries provide
// the cross-XCD coherence) — used if cooperative launch is rejected.
// ---------------------------------------------------------------------------
__global__ __launch_bounds__(256) void prep_kernel(
    const float* __restrict__ Wk, const float* __restrict__ Wv,
    const float* __restrict__ Wq, const float* __restrict__ Wg,
    const float* __restrict__ Wback,
    const void* __restrict__ mraw, const void* __restrict__ braw,
    unsigned short* __restrict__ WkT, unsigned short* __restrict__ WvT,
    unsigned short* __restrict__ WqT, unsigned short* __restrict__ WgT,
    unsigned short* __restrict__ WbackT,
    float* __restrict__ mask_f, int* __restrict__ seg)
{
    __shared__ __align__(16) char smem[8320];
    phase_prep(blockIdx.x, threadIdx.x, smem, Wk, Wv, Wq, Wg, Wback, mraw, braw,
               WkT, WvT, WqT, WgT, WbackT, mask_f, seg);
}

__global__ __launch_bounds__(256, 2) void proj_kernel(
    const float* __restrict__ emb, const float* __restrict__ x,
    const unsigned short* __restrict__ WkT, const unsigned short* __restrict__ WvT,
    const unsigned short* __restrict__ WqT, const unsigned short* __restrict__ WgT,
    const float* __restrict__ bg,
    unsigned short* __restrict__ k_blk, unsigned short* __restrict__ vT_bf,
    unsigned short* __restrict__ q_bf, float* __restrict__ gate_ws)
{
    __shared__ __align__(16) char smem[16640];
    phase_proj(blockIdx.x, threadIdx.x, smem, emb, x, WkT, WvT, WqT, WgT, bg,
               k_blk, vT_bf, q_bf, gate_ws);
}

__global__ __launch_bounds__(256, 2) void attn_kernel(
    const unsigned short* __restrict__ k_blk, const unsigned short* __restrict__ vT_bf,
    const unsigned short* __restrict__ q_bf, const float* __restrict__ mask_f,
    const int* __restrict__ seg, unsigned short* __restrict__ part_O,
    float2* __restrict__ part_ml, float* __restrict__ out_logits)
{
    __shared__ __align__(16) char smem[34304];
    phase_attn(blockIdx.x, threadIdx.x, smem, k_blk, vT_bf, q_bf, mask_f, seg,
               part_O, part_ml, out_logits);
}

__global__ __launch_bounds__(256, 2) void back_kernel(
    const unsigned short* __restrict__ part_O, const float2* __restrict__ part_ml,
    const float* __restrict__ gate_ws, const unsigned short* __restrict__ WbackT,
    const float* __restrict__ x, const float* __restrict__ bback,
    const float* __restrict__ gamma, const float* __restrict__ beta,
    float* __restrict__ out)
{
    __shared__ __align__(16) char smem[18688];
    phase_back(blockIdx.x, threadIdx.x, smem, part_O, part_ml, gate_ws, WbackT, x,
               bback, gamma, beta, out);
}

extern "C" void kernel_launch(void* const* d_in, const int* in_sizes, int n_in,
                              void* d_out, int out_size, void* d_ws, size_t ws_size,
                              hipStream_t stream) {
    const float* x     = (const float*)d_in[0];
    const float* emb   = (const float*)d_in[1];
    const void*  mraw  = d_in[2];
    const void*  braw  = d_in[3];
    const float* Wq    = (const float*)d_in[4];
    const float* Wk    = (const float*)d_in[5];
    const float* Wv    = (const float*)d_in[6];
    const float* Wg    = (const float*)d_in[7];
    const float* bg    = (const float*)d_in[8];
    const float* Wback = (const float*)d_in[9];
    const float* bback = (const float*)d_in[10];
    const float* gamma = (const float*)d_in[11];
    const float* beta  = (const float*)d_in[12];

    char* ws = (char*)d_ws;
    const size_t MB = 1048576;
    size_t off = 0;
    float*          mask_f  = (float*)(ws + off);  off += 16384;
    int*            seg     = (int*)(ws + off);    off += 16384;
    unsigned short* WkT     = (unsigned short*)(ws + off); off += 393216;
    unsigned short* WvT     = (unsigned short*)(ws + off); off += 393216;
    unsigned short* WqT     = (unsigned short*)(ws + off); off += 262144;
    unsigned short* WgT     = (unsigned short*)(ws + off); off += 262144;
    unsigned short* WbackT  = (unsigned short*)(ws + off); off += 262144;
    unsigned short* k_blk   = (unsigned short*)(ws + off); off += 4*MB;
    unsigned short* vT_bf   = (unsigned short*)(ws + off); off += 4*MB;
    unsigned short* q_bf    = (unsigned short*)(ws + off); off += 2*MB;
    float*          gate_ws = (float*)(ws + off); off += 4*MB;
    unsigned short* part_O  = (unsigned short*)(ws + off); off += 16*MB;
    float2*         part_ml = (float2*)(ws + off); off += 1*MB;

    float* out        = (float*)d_out;
    float* out_logits = out + (size_t)NND * IFZ;

    void* args[] = {
        (void*)&emb, (void*)&x, (void*)&Wk, (void*)&Wv, (void*)&Wq, (void*)&Wg,
        (void*)&Wback, (void*)&mraw, (void*)&braw, (void*)&bg, (void*)&bback,
        (void*)&gamma, (void*)&beta,
        (void*)&WkT, (void*)&WvT, (void*)&WqT, (void*)&WgT, (void*)&WbackT,
        (void*)&mask_f, (void*)&seg, (void*)&k_blk, (void*)&vT_bf, (void*)&q_bf,
        (void*)&gate_ws, (void*)&part_O, (void*)&part_ml, (void*)&out, (void*)&out_logits
    };
    hipError_t err = hipLaunchCooperativeKernel((void*)fused_all, dim3(GRID_BLKS),
                                                dim3(256), args, 0, stream);
    if (err != hipSuccess) {
        (void)hipGetLastError();   // clear sticky error, use 4-dispatch fallback
        hipLaunchKernelGGL(prep_kernel, dim3(193), dim3(256), 0, stream,
                           Wk, Wv, Wq, Wg, Wback, mraw, braw,
                           WkT, WvT, WqT, WgT, WbackT, mask_f, seg);
        hipLaunchKernelGGL(proj_kernel, dim3(512), dim3(256), 0, stream,
                           emb, x, WkT, WvT, WqT, WgT, bg, k_blk, vT_bf, q_bf, gate_ws);
        hipLaunchKernelGGL(attn_kernel, dim3(BBATCH * ABLK * 16), dim3(256), 0, stream,
                           k_blk, vT_bf, q_bf, mask_f, seg, part_O, part_ml, out_logits);
        hipLaunchKernelGGL(back_kernel, dim3(NND / 8), dim3(256), 0, stream,
                           part_O, part_ml, gate_ws, WbackT, x, bback, gamma, beta, out);
    }
}

// Round 7
// 186.795 us; speedup vs baseline: 3.3369x; 3.3369x over previous
//
#include <hip/hip_runtime.h>
#include <hip/hip_bf16.h>

#define NND 2048
#define BBATCH 4
#define SS 1024
#define SFZ 384
#define IFZ 256
#define HH 8
#define AA 64
#define HA 512
#define ABLK 12   // 64-node x-blocks per batch (768-node capacity, 13 sigma)
#define NGRP 4    // 16-node groups per x-block
#define NSPL 8    // S-splits in attention

typedef __attribute__((ext_vector_type(8))) short bf16x8;
typedef __attribute__((ext_vector_type(4))) float f32x4;
typedef __attribute__((ext_vector_type(2))) unsigned int u32x2;

__device__ __forceinline__ unsigned short f2bf(float f) {
    union { float f; unsigned u; } a; a.f = f;
    unsigned r = a.u + 0x7fffu + ((a.u >> 16) & 1u);
    return (unsigned short)(r >> 16);
}
__device__ __forceinline__ float bf2f(unsigned short u) {
    return __uint_as_float((unsigned)u << 16);
}

__device__ __forceinline__ bf16x8 cvt8(const float* __restrict__ p) {
    const float4 f0 = *(const float4*)p;
    const float4 f1 = *(const float4*)(p + 4);
    bf16x8 o;
    o[0] = (short)f2bf(f0.x); o[1] = (short)f2bf(f0.y);
    o[2] = (short)f2bf(f0.z); o[3] = (short)f2bf(f0.w);
    o[4] = (short)f2bf(f1.x); o[5] = (short)f2bf(f1.y);
    o[6] = (short)f2bf(f1.z); o[7] = (short)f2bf(f1.w);
    return o;
}

// --- forced-issue async loads (asm volatile preserves issue order) ---
__device__ __forceinline__ bf16x8 gld16(const unsigned short* p) {
    bf16x8 r;
    asm volatile("global_load_dwordx4 %0, %1, off" : "=&v"(r) : "v"(p));
    return r;
}
__device__ __forceinline__ f32x4 gldf4(const float* p) {
    f32x4 r;
    asm volatile("global_load_dwordx4 %0, %1, off" : "=&v"(r) : "v"(p));
    return r;
}
__device__ __forceinline__ u32x2 gld8(const unsigned short* p) {
    u32x2 r;
    asm volatile("global_load_dwordx2 %0, %1, off" : "=&v"(r) : "v"(p));
    return r;
}
#define VMWAIT0() do { \
    asm volatile("s_waitcnt vmcnt(0)" ::: "memory"); \
    __builtin_amdgcn_sched_barrier(0); \
} while (0)

// ---------------------------------------------------------------------------
// Kernel P: prep. Blocks 0..191: weight transposes fp32->bf16.
// Block 192: detect mask/batch dtype -> mask_f, seg.
// ---------------------------------------------------------------------------
__device__ __forceinline__ void tile_transpose(
    const float* __restrict__ src, unsigned short* __restrict__ dst,
    int K, int N, int kt, int nt, int t)
{
    __shared__ unsigned short tile[64][65];
    const int k0 = kt * 64, n0 = nt * 64;
    const int tr = t >> 6, tc = t & 63;
    #pragma unroll
    for (int r = 0; r < 16; ++r)
        tile[tr + r*4][tc] = f2bf(src[(size_t)(k0 + tr + r*4) * N + n0 + tc]);
    __syncthreads();
    #pragma unroll
    for (int r = 0; r < 16; ++r)
        dst[(size_t)(n0 + tr + r*4) * K + k0 + tc] = tile[tc][tr + r*4];
}

__global__ __launch_bounds__(256) void prep_kernel(
    const float* __restrict__ Wk, const float* __restrict__ Wv,
    const float* __restrict__ Wq, const float* __restrict__ Wg,
    const float* __restrict__ Wback,
    const void* __restrict__ mask_raw, const void* __restrict__ batch_raw,
    unsigned short* __restrict__ WkT, unsigned short* __restrict__ WvT,
    unsigned short* __restrict__ WqT, unsigned short* __restrict__ WgT,
    unsigned short* __restrict__ WbackT,
    float* __restrict__ mask_f, int* __restrict__ seg)
{
    const int bx = blockIdx.x, t = threadIdx.x;
    if (bx < 48)  { tile_transpose(Wk, WkT, SFZ, HA, bx/8, bx%8, t); return; }
    if (bx < 96)  { const int i = bx-48;  tile_transpose(Wv, WvT, SFZ, HA, i/8, i%8, t); return; }
    if (bx < 128) { const int i = bx-96;  tile_transpose(Wq, WqT, IFZ, HA, i/8, i%8, t); return; }
    if (bx < 160) { const int i = bx-128; tile_transpose(Wg, WgT, IFZ, HA, i/8, i%8, t); return; }
    if (bx < 192) { const int i = bx-160; tile_transpose(Wback, WbackT, HA, IFZ, i/4, i%4, t); return; }
    __shared__ int fl[4];
    __shared__ int fb;
    __shared__ int cnt[4];
    if (t < 4) { fl[t] = 0; cnt[t] = 0; }
    if (t == 0) fb = 0;
    __syncthreads();
    const unsigned char*  mb = (const unsigned char*)mask_raw;
    const unsigned short* mh = (const unsigned short*)mask_raw;
    const unsigned int*   mw = (const unsigned int*)mask_raw;
    int f0 = 0, f1 = 0, f2 = 0, f3 = 0;
    for (int i = t; i < 2048; i += 256) {
        unsigned short h = mh[i];
        if (h == 0x3f80u) f0 = 1;
        if ((i & 1) == 0 && h != 0) f1 = 1;
    }
    for (int i = t; i < 4096; i += 256)
        if ((i & 3) != 0 && mb[i] != 0) f2 = 1;
    for (int i = t; i < 1024; i += 256)
        if ((i & 1) != 0 && mw[i] != 0) f3 = 1;
    const int* bw = (const int*)batch_raw;
    int f4 = 0;
    for (int i = t + 1; i < 2048; i += 256)
        if (bw[i] < bw[i-1]) f4 = 1;
    if (f0) atomicOr(&fl[0], 1);
    if (f1) atomicOr(&fl[1], 1);
    if (f2) atomicOr(&fl[2], 1);
    if (f3) atomicOr(&fl[3], 1);
    if (f4) atomicOr(&fb, 1);
    __syncthreads();
    int mode;
    if (fl[0])      mode = fl[1] ? 1 : 0;
    else if (fl[2]) mode = 2;
    else if (fl[3]) mode = 3;
    else            mode = 4;
    for (int s = t; s < BBATCH*SS; s += 256) {
        int m;
        switch (mode) {
            case 0:  m = (mw[s]   != 0); break;
            case 1:  m = (mh[s]   != 0); break;
            case 2:  m = (mb[s]   != 0); break;
            case 3:  m = (mw[s]   != 0); break;
            default: m = (mw[2*s] != 0); break;
        }
        mask_f[s] = m ? 1.0f : 0.0f;
    }
    const int b64 = fb;
    for (int i = t; i < NND; i += 256) {
        const int bv = (b64 ? bw[2*i] : bw[i]) & 3;
        atomicAdd(&cnt[bv], 1);
    }
    __syncthreads();
    if (t == 0) {
        int s = 0;
        for (int b = 0; b < 4; ++b) { seg[2*b] = s; s += cnt[b]; seg[2*b+1] = s; }
    }
}

// ---------------------------------------------------------------------------
// Kernel 1: fused MFMA projections (merged k+v / q+gate, R4 form).
// ---------------------------------------------------------------------------
__global__ __launch_bounds__(256, 2) void proj_mfma(
    const float* __restrict__ emb, const float* __restrict__ x,
    const unsigned short* __restrict__ WkT, const unsigned short* __restrict__ WvT,
    const unsigned short* __restrict__ WqT, const unsigned short* __restrict__ WgT,
    const float* __restrict__ bg,
    unsigned short* __restrict__ k_blk, unsigned short* __restrict__ vT_bf,
    unsigned short* __restrict__ q_bf, float* __restrict__ gate_ws)
{
    __shared__ unsigned short v_l[16][520];   // 16.6 KB
    const int t = threadIdx.x, w = t >> 6, lane = t & 63;
    const int m16 = lane & 15, quad = lane >> 4;
    const int bx = blockIdx.x;
    if (bx < 256) {
        const int r0 = bx * 16;
        const int b = r0 >> 10, srow = r0 & (SS - 1);
        const float* ap = emb + (size_t)(r0 + m16) * SFZ + quad * 8;
        bf16x8 af[12];
        #pragma unroll
        for (int j = 0; j < 12; ++j) af[j] = cvt8(ap + j * 32);
        #pragma unroll
        for (int tensor = 0; tensor < 2; ++tensor) {
            const unsigned short* Wt = tensor ? WvT : WkT;
            #pragma unroll
            for (int g = 0; g < 2; ++g) {
                const int n0g = w * 128 + g * 64;
                const unsigned short* bp0 = Wt + (size_t)(n0g +  0 + m16) * SFZ + quad * 8;
                const unsigned short* bp1 = Wt + (size_t)(n0g + 16 + m16) * SFZ + quad * 8;
                const unsigned short* bp2 = Wt + (size_t)(n0g + 32 + m16) * SFZ + quad * 8;
                const unsigned short* bp3 = Wt + (size_t)(n0g + 48 + m16) * SFZ + quad * 8;
                f32x4 a0 = (f32x4){0.f, 0.f, 0.f, 0.f};
                f32x4 a1 = a0, a2 = a0, a3 = a0;
                bf16x8 wb[24];
                #pragma unroll
                for (int j = 0; j < 6; ++j) {
                    wb[j*4+0] = gld16(bp0 + j * 32);
                    wb[j*4+1] = gld16(bp1 + j * 32);
                    wb[j*4+2] = gld16(bp2 + j * 32);
                    wb[j*4+3] = gld16(bp3 + j * 32);
                }
                VMWAIT0();
                #pragma unroll
                for (int j = 0; j < 6; ++j) {
                    a0 = __builtin_amdgcn_mfma_f32_16x16x32_bf16(af[j], wb[j*4+0], a0, 0, 0, 0);
                    a1 = __builtin_amdgcn_mfma_f32_16x16x32_bf16(af[j], wb[j*4+1], a1, 0, 0, 0);
                    a2 = __builtin_amdgcn_mfma_f32_16x16x32_bf16(af[j], wb[j*4+2], a2, 0, 0, 0);
                    a3 = __builtin_amdgcn_mfma_f32_16x16x32_bf16(af[j], wb[j*4+3], a3, 0, 0, 0);
                }
                #pragma unroll
                for (int j = 6; j < 12; ++j) {
                    wb[(j-6)*4+0] = gld16(bp0 + j * 32);
                    wb[(j-6)*4+1] = gld16(bp1 + j * 32);
                    wb[(j-6)*4+2] = gld16(bp2 + j * 32);
                    wb[(j-6)*4+3] = gld16(bp3 + j * 32);
                }
                VMWAIT0();
                #pragma unroll
                for (int j = 6; j < 12; ++j) {
                    a0 = __builtin_amdgcn_mfma_f32_16x16x32_bf16(af[j], wb[(j-6)*4+0], a0, 0, 0, 0);
                    a1 = __builtin_amdgcn_mfma_f32_16x16x32_bf16(af[j], wb[(j-6)*4+1], a1, 0, 0, 0);
                    a2 = __builtin_amdgcn_mfma_f32_16x16x32_bf16(af[j], wb[(j-6)*4+2], a2, 0, 0, 0);
                    a3 = __builtin_amdgcn_mfma_f32_16x16x32_bf16(af[j], wb[(j-6)*4+3], a3, 0, 0, 0);
                }
                f32x4 dd[4] = {a0, a1, a2, a3};
                if (tensor == 0) {
                    #pragma unroll
                    for (int u = 0; u < 4; ++u) {
                        const int n0 = n0g + u * 16;
                        const int head = n0 >> 6, coff = (n0 & 63) + m16;
                        unsigned short* kb = k_blk + (((size_t)(b * HH + head)) * SS) * 64 + coff;
                        #pragma unroll
                        for (int r = 0; r < 4; ++r)
                            kb[(size_t)(srow + quad * 4 + r) * 64] = f2bf(dd[u][r]);
                    }
                } else {
                    #pragma unroll
                    for (int u = 0; u < 4; ++u) {
                        const int c0 = n0g + u * 16 + m16;
                        #pragma unroll
                        for (int r = 0; r < 4; ++r)
                            v_l[quad * 4 + r][c0] = f2bf(dd[u][r]);
                    }
                }
            }
        }
        __syncthreads();
        for (int c = t; c < HA; c += 256) {
            unsigned short tmp[16];
            #pragma unroll
            for (int s = 0; s < 16; ++s) tmp[s] = v_l[s][c];
            unsigned short* dst = vT_bf + ((size_t)b * HA + c) * SS + srow;
            *(uint4*)dst       = ((const uint4*)tmp)[0];
            *(uint4*)(dst + 8) = ((const uint4*)tmp)[1];
        }
    } else {
        const int i = bx - 256;
        const int r0 = (i >> 1) * 16;
        const int half = i & 1;
        const float* ap = x + (size_t)(r0 + m16) * IFZ + quad * 8;
        bf16x8 af[8];
        #pragma unroll
        for (int j = 0; j < 8; ++j) af[j] = cvt8(ap + j * 32);
        const int n0b = half * 256 + w * 64;
        #pragma unroll
        for (int tensor = 0; tensor < 2; ++tensor) {
            const unsigned short* Wt = tensor ? WgT : WqT;
            const unsigned short* bp0 = Wt + (size_t)(n0b +  0 + m16) * IFZ + quad * 8;
            const unsigned short* bp1 = Wt + (size_t)(n0b + 16 + m16) * IFZ + quad * 8;
            const unsigned short* bp2 = Wt + (size_t)(n0b + 32 + m16) * IFZ + quad * 8;
            const unsigned short* bp3 = Wt + (size_t)(n0b + 48 + m16) * IFZ + quad * 8;
            bf16x8 wb[32];
            #pragma unroll
            for (int j = 0; j < 8; ++j) {
                wb[j*4+0] = gld16(bp0 + j * 32);
                wb[j*4+1] = gld16(bp1 + j * 32);
                wb[j*4+2] = gld16(bp2 + j * 32);
                wb[j*4+3] = gld16(bp3 + j * 32);
            }
            VMWAIT0();
            f32x4 a0 = (f32x4){0.f, 0.f, 0.f, 0.f};
            f32x4 a1 = a0, a2 = a0, a3 = a0;
            #pragma unroll
            for (int j = 0; j < 8; ++j) {
                a0 = __builtin_amdgcn_mfma_f32_16x16x32_bf16(af[j], wb[j*4+0], a0, 0, 0, 0);
                a1 = __builtin_amdgcn_mfma_f32_16x16x32_bf16(af[j], wb[j*4+1], a1, 0, 0, 0);
                a2 = __builtin_amdgcn_mfma_f32_16x16x32_bf16(af[j], wb[j*4+2], a2, 0, 0, 0);
                a3 = __builtin_amdgcn_mfma_f32_16x16x32_bf16(af[j], wb[j*4+3], a3, 0, 0, 0);
            }
            f32x4 dd[4] = {a0, a1, a2, a3};
            if (tensor == 0) {
                #pragma unroll
                for (int u = 0; u < 4; ++u) {
                    const int n0 = n0b + u * 16;
                    #pragma unroll
                    for (int r = 0; r < 4; ++r)
                        q_bf[(size_t)(r0 + quad * 4 + r) * HA + n0 + m16] = f2bf(dd[u][r]);
                }
            } else {
                #pragma unroll
                for (int u = 0; u < 4; ++u) {
                    const int n0 = n0b + u * 16;
                    const float bgv = bg[n0 + m16];
                    #pragma unroll
                    for (int r = 0; r < 4; ++r)
                        gate_ws[(size_t)(r0 + quad * 4 + r) * HA + n0 + m16] =
                            1.f / (1.f + __expf(-(dd[u][r] + bgv)));
                }
            }
        }
    }
}

// ---------------------------------------------------------------------------
// Kernel 3: flash attention, swapped-QK^T lane-local softmax version.
// Grid 768: (b via XCD pair) x (xblk of 64 nodes) x (hz, split).
// mfma(K,Q): C[row=s][col=node] -> each lane owns ONE node's 32 scores.
// Softmax = in-lane tree + 2 shuffles (was 4 rows x 4-shuffle chains).
// K in regs across groups; V + next-q issued after QK, hidden by softmax;
// single vmcnt(0) per group before PV (also retires prior stores for free).
// ---------------------------------------------------------------------------
__global__ __launch_bounds__(256, 2) void attn_kernel(
    const unsigned short* __restrict__ k_blk, const unsigned short* __restrict__ vT_bf,
    const unsigned short* __restrict__ q_bf, const float* __restrict__ mask_f,
    const int* __restrict__ seg, unsigned short* __restrict__ part_O,
    float2* __restrict__ part_ml, float* __restrict__ out_logits)
{
    __shared__ unsigned short P_lds[4][16][136];   // 17.4 KB
    __shared__ float raw[2][16][132];              // 16.9 KB (hz==0 logits stash)
    const int bid = blockIdx.x;
    const int xcd = bid & 7;
    const int b   = xcd >> 1;
    const int idx = (bid >> 3) * 2 + (xcd & 1);   // [0,192)
    const int z    = idx & 15;
    const int xblk = idx >> 4;                    // [0,12)
    const int hz    = z >> 3;
    const int split = z & 7;
    const int nbase = seg[2*b] + xblk * (16 * NGRP);
    const int nend  = seg[2*b + 1];
    if (nbase >= nend) return;

    const int t = threadIdx.x;
    const int w = t >> 6, lane = t & 63;
    const int m16 = lane & 15, quad = lane >> 4;
    const int h = hz * 4 + w;
    const int s0 = split * 128;

    const unsigned short* kb = k_blk + ((size_t)(b * HH + h)) * SS * 64;
    const unsigned short* vb = vT_bf + ((size_t)b * HA + h * AA) * SS;
    const unsigned short* qbase = q_bf + (size_t)h * AA + quad * 8;
    unsigned short (*Pw)[136] = P_lds[w];

    // ---- prologue burst: K(16) + mask(8) + q0(2) ----
    bf16x8 kf[16];
    #pragma unroll
    for (int st = 0; st < 8; ++st) {
        const unsigned short* kp = kb + (size_t)(s0 + st * 16 + m16) * 64 + quad * 8;
        kf[2*st]   = gld16(kp);
        kf[2*st+1] = gld16(kp + 32);
    }
    f32x4 mkv[8];
    #pragma unroll
    for (int st = 0; st < 8; ++st)
        mkv[st] = gldf4(mask_f + b * SS + s0 + st * 16 + quad * 4);
    int nq0 = nbase + m16; if (nq0 >= nend) nq0 = nend - 1;
    bf16x8 qc0 = gld16(qbase + (size_t)nq0 * HA);
    bf16x8 qc1 = gld16(qbase + (size_t)nq0 * HA + 32);
    VMWAIT0();
    // ---- per-lane mask bitmask: bit (st*4+r) <-> s = st*16 + quad*4 + r ----
    unsigned bm = 0u;
    #pragma unroll
    for (int st = 0; st < 8; ++st)
        #pragma unroll
        for (int r = 0; r < 4; ++r)
            if (mkv[st][r] > 0.5f) bm |= (1u << (st * 4 + r));

    bf16x8 qn0 = qc0, qn1 = qc1;
    for (int g = 0; g < NGRP; ++g) {
        const int n0g = nbase + g * 16;
        if (n0g >= nend) break;                     // block-uniform
        const int nvalid = min(16, nend - n0g);

        // ---- QK^T swapped: C[row=s(st*16+quad*4+r)][col=node(m16)] ----
        f32x4 d[8];
        #pragma unroll
        for (int st = 0; st < 8; ++st) {
            f32x4 acc = (f32x4){0.f, 0.f, 0.f, 0.f};
            acc = __builtin_amdgcn_mfma_f32_16x16x32_bf16(kf[2*st],   qc0, acc, 0, 0, 0);
            acc = __builtin_amdgcn_mfma_f32_16x16x32_bf16(kf[2*st+1], qc1, acc, 0, 0, 0);
            #pragma unroll
            for (int r = 0; r < 4; ++r) acc[r] *= 0.125f;
            d[st] = acc;
        }
        // ---- issue V burst + next-q; softmax/logits hide their latency ----
        bf16x8 vf[16];
        #pragma unroll
        for (int sub = 0; sub < 4; ++sub) {
            const unsigned short* vp0 = vb + (size_t)m16 * SS + s0 + sub * 32 + quad * 8;
            #pragma unroll
            for (int a = 0; a < 4; ++a)
                vf[sub*4+a] = gld16(vp0 + (size_t)(a * 16) * SS);
        }
        if (g + 1 < NGRP && nbase + (g + 1) * 16 < nend) {
            int nqn = nbase + (g + 1) * 16 + m16; if (nqn >= nend) nqn = nend - 1;
            qn0 = gld16(qbase + (size_t)nqn * HA);
            qn1 = gld16(qbase + (size_t)nqn * HA + 32);
        }
        __builtin_amdgcn_sched_barrier(0);

        // ---- fused logits (hz==0): w0/w1 stash -> coalesced combined store ----
        if (hz == 0) {
            if (w < 2) {
                #pragma unroll
                for (int st = 0; st < 8; ++st)
                    *(float4*)&raw[w][m16][st * 16 + quad * 4] =
                        make_float4(d[st][0], d[st][1], d[st][2], d[st][3]);
            }
            __syncthreads();
            for (int i = t; i < 16 * 128; i += 256) {
                const int node = i >> 7, sp = i & 127;
                if (node < nvalid)
                    out_logits[(size_t)(n0g + node) * SS + s0 + sp] =
                        raw[0][node][sp] + raw[1][node][sp];
            }
            __syncthreads();
        }
        // ---- lane-local masked softmax (node = m16, per lane) ----
        #pragma unroll
        for (int st = 0; st < 8; ++st)
            #pragma unroll
            for (int r = 0; r < 4; ++r)
                if (!((bm >> (st * 4 + r)) & 1u)) d[st][r] = -3.0e38f;
        float mx = -3.0e38f;
        #pragma unroll
        for (int st = 0; st < 8; ++st) {
            float a = fmaxf(fmaxf(d[st][0], d[st][1]), fmaxf(d[st][2], d[st][3]));
            mx = fmaxf(mx, a);
        }
        mx = fmaxf(mx, __shfl_xor(mx, 16));
        mx = fmaxf(mx, __shfl_xor(mx, 32));
        mx = fmaxf(mx, -1.0e30f);      // all-masked rows -> exp underflow -> l=0
        float cs = 0.f;
        #pragma unroll
        for (int st = 0; st < 8; ++st)
            #pragma unroll
            for (int r = 0; r < 4; ++r) {
                const float e = __expf(d[st][r] - mx);
                d[st][r] = e;
                cs += e;
            }
        cs += __shfl_xor(cs, 16);
        cs += __shfl_xor(cs, 32);
        // ---- P -> LDS: lane owns node m16, 4 contiguous bf16 per st ----
        #pragma unroll
        for (int st = 0; st < 8; ++st) {
            ushort4 pk;
            pk.x = f2bf(d[st][0]); pk.y = f2bf(d[st][1]);
            pk.z = f2bf(d[st][2]); pk.w = f2bf(d[st][3]);
            *(ushort4*)&Pw[m16][st * 16 + quad * 4] = pk;
        }
        bf16x8 pa[4];
        #pragma unroll
        for (int sub = 0; sub < 4; ++sub)
            pa[sub] = *(const bf16x8*)&Pw[m16][sub * 32 + quad * 8];
        // ---- wait V (+q, +prior stores retired); PV with zero stalls ----
        VMWAIT0();
        f32x4 facc[4];
        #pragma unroll
        for (int a = 0; a < 4; ++a) facc[a] = (f32x4){0.f, 0.f, 0.f, 0.f};
        #pragma unroll
        for (int sub = 0; sub < 4; ++sub) {
            #pragma unroll
            for (int a = 0; a < 4; ++a)
                facc[a] = __builtin_amdgcn_mfma_f32_16x16x32_bf16(pa[sub], vf[sub*4+a], facc[a], 0, 0, 0);
        }
        // ---- epilogue: partial O (C row=node) + per-node (m,l) ----
        unsigned short* po = part_O + (size_t)split * NND * HA;
        #pragma unroll
        for (int a = 0; a < 4; ++a)
            #pragma unroll
            for (int r = 0; r < 4; ++r) {
                const int row = quad * 4 + r;
                if (row < nvalid)
                    po[(size_t)(n0g + row) * HA + h * AA + a * 16 + m16] = f2bf(facc[a][r]);
            }
        if (quad == 0 && m16 < nvalid)
            part_ml[(size_t)split * NND * HH + (size_t)(n0g + m16) * HH + h] =
                make_float2(mx, cs);
        qc0 = qn0; qc1 = qn1;
    }
}

// ---------------------------------------------------------------------------
// Kernel 4: fused combine(8 splits) + gate mul + Wback MFMA + residual + LN.
// ---------------------------------------------------------------------------
__global__ __launch_bounds__(256, 2) void back_ln_fused(
    const unsigned short* __restrict__ part_O, const float2* __restrict__ part_ml,
    const float* __restrict__ gate_ws, const unsigned short* __restrict__ WbackT,
    const float* __restrict__ x, const float* __restrict__ bback,
    const float* __restrict__ gamma, const float* __restrict__ beta,
    float* __restrict__ out)
{
    __shared__ float coef[NSPL][8][8];
    __shared__ unsigned short gf_l[8][520];
    __shared__ float nl[8][260];
    const int t = threadIdx.x, w = t >> 6, lane = t & 63;
    const int m16 = lane & 15, quad = lane >> 4;
    const int r0 = blockIdx.x * 8;
    if (t < 64) {
        const int row = t >> 3, h = t & 7, n = r0 + row;
        float2 ml[NSPL];
        #pragma unroll
        for (int s = 0; s < NSPL; ++s)
            ml[s] = part_ml[(size_t)s * NND * HH + (size_t)n * HH + h];
        float M = -3.0e38f;
        #pragma unroll
        for (int s = 0; s < NSPL; ++s) M = fmaxf(M, ml[s].x);
        float L = 0.f;
        float e[NSPL];
        #pragma unroll
        for (int s = 0; s < NSPL; ++s) { e[s] = __expf(ml[s].x - M); L += ml[s].y * e[s]; }
        const float invL = 1.f / (L + 1e-9f);
        #pragma unroll
        for (int s = 0; s < NSPL; ++s) coef[s][row][h] = e[s] * invL;
    }
    u32x2 pvv[4][NSPL];
    f32x4 gv[4];
    #pragma unroll
    for (int it = 0; it < 4; ++it) {
        const int i = (t + it * 256) * 4;
        const int row = i >> 9, c = i & (HA - 1);
        const int n = r0 + row;
        #pragma unroll
        for (int s = 0; s < NSPL; ++s)
            pvv[it][s] = gld8(&part_O[(size_t)s * NND * HA + (size_t)n * HA + c]);
        gv[it] = gldf4(&gate_ws[(size_t)n * HA + c]);
    }
    __syncthreads();   // coef ready
    VMWAIT0();
    #pragma unroll
    for (int it = 0; it < 4; ++it) {
        const int i = (t + it * 256) * 4;
        const int row = i >> 9, c = i & (HA - 1), h = c >> 6;
        float4 o = make_float4(0.f, 0.f, 0.f, 0.f);
        #pragma unroll
        for (int s = 0; s < NSPL; ++s) {
            const float cf = coef[s][row][h];
            o.x = fmaf(bf2f((unsigned short)(pvv[it][s][0] & 0xffffu)), cf, o.x);
            o.y = fmaf(bf2f((unsigned short)(pvv[it][s][0] >> 16)),     cf, o.y);
            o.z = fmaf(bf2f((unsigned short)(pvv[it][s][1] & 0xffffu)), cf, o.z);
            o.w = fmaf(bf2f((unsigned short)(pvv[it][s][1] >> 16)),     cf, o.w);
        }
        ushort4 ob;
        ob.x = f2bf(gv[it][0] * o.x); ob.y = f2bf(gv[it][1] * o.y);
        ob.z = f2bf(gv[it][2] * o.z); ob.w = f2bf(gv[it][3] * o.w);
        *(ushort4*)&gf_l[row][c] = ob;
    }
    __syncthreads();
    bf16x8 af[16];
    #pragma unroll
    for (int j = 0; j < 16; ++j)
        af[j] = *(const bf16x8*)&gf_l[m16 & 7][quad * 8 + j * 32];
    const unsigned short* bq0 = WbackT + (size_t)(w * 64 +  0 + m16) * HA + quad * 8;
    const unsigned short* bq1 = WbackT + (size_t)(w * 64 + 16 + m16) * HA + quad * 8;
    const unsigned short* bq2 = WbackT + (size_t)(w * 64 + 32 + m16) * HA + quad * 8;
    const unsigned short* bq3 = WbackT + (size_t)(w * 64 + 48 + m16) * HA + quad * 8;
    f32x4 a0 = (f32x4){0.f, 0.f, 0.f, 0.f};
    f32x4 a1 = a0, a2 = a0, a3 = a0;
    #pragma unroll
    for (int jb = 0; jb < 4; ++jb) {
        bf16x8 wb[16];
        #pragma unroll
        for (int j = 0; j < 4; ++j) {
            wb[j*4+0] = gld16(bq0 + (jb*4 + j) * 32);
            wb[j*4+1] = gld16(bq1 + (jb*4 + j) * 32);
            wb[j*4+2] = gld16(bq2 + (jb*4 + j) * 32);
            wb[j*4+3] = gld16(bq3 + (jb*4 + j) * 32);
        }
        VMWAIT0();
        #pragma unroll
        for (int j = 0; j < 4; ++j) {
            a0 = __builtin_amdgcn_mfma_f32_16x16x32_bf16(af[jb*4+j], wb[j*4+0], a0, 0, 0, 0);
            a1 = __builtin_amdgcn_mfma_f32_16x16x32_bf16(af[jb*4+j], wb[j*4+1], a1, 0, 0, 0);
            a2 = __builtin_amdgcn_mfma_f32_16x16x32_bf16(af[jb*4+j], wb[j*4+2], a2, 0, 0, 0);
            a3 = __builtin_amdgcn_mfma_f32_16x16x32_bf16(af[jb*4+j], wb[j*4+3], a3, 0, 0, 0);
        }
    }
    {
        f32x4 dd[4] = {a0, a1, a2, a3};
        #pragma unroll
        for (int u = 0; u < 4; ++u) {
            const int n0 = w * 64 + u * 16;
            const float bb = bback[n0 + m16];
            #pragma unroll
            for (int r = 0; r < 4; ++r) {
                const int rr = quad * 4 + r;
                if (rr < 8) nl[rr][n0 + m16] = dd[u][r] + bb;
            }
        }
    }
    __syncthreads();
    const int row = t >> 5, li = t & 31;
    const float* xr = x + (size_t)(r0 + row) * IFZ;
    float yv[8];
    float s1 = 0.f, s2 = 0.f;
    #pragma unroll
    for (int j = 0; j < 8; ++j) {
        const int c = li + j * 32;
        const float v = fmaf(1.41421356237309515f, xr[c], nl[row][c]);
        yv[j] = v; s1 += v; s2 += v * v;
    }
    #pragma unroll
    for (int off = 16; off >= 1; off >>= 1) {
        s1 += __shfl_xor(s1, off);
        s2 += __shfl_xor(s2, off);
    }
    const float mu  = s1 * (1.f / IFZ);
    const float var = s2 * (1.f / IFZ) - mu * mu;
    const float rv  = rsqrtf(var + 1e-5f);
    float* orow = out + (size_t)(r0 + row) * IFZ;
    #pragma unroll
    for (int j = 0; j < 8; ++j) {
        const int c = li + j * 32;
        orow[c] = (yv[j] - mu) * rv * gamma[c] + beta[c];
    }
}

extern "C" void kernel_launch(void* const* d_in, const int* in_sizes, int n_in,
                              void* d_out, int out_size, void* d_ws, size_t ws_size,
                              hipStream_t stream) {
    const float* x     = (const float*)d_in[0];
    const float* emb   = (const float*)d_in[1];
    const void*  mraw  = d_in[2];
    const void*  braw  = d_in[3];
    const float* Wq    = (const float*)d_in[4];
    const float* Wk    = (const float*)d_in[5];
    const float* Wv    = (const float*)d_in[6];
    const float* Wg    = (const float*)d_in[7];
    const float* bg    = (const float*)d_in[8];
    const float* Wback = (const float*)d_in[9];
    const float* bback = (const float*)d_in[10];
    const float* gamma = (const float*)d_in[11];
    const float* beta  = (const float*)d_in[12];

    char* ws = (char*)d_ws;
    const size_t MB = 1048576;
    size_t off = 0;
    float*          mask_f  = (float*)(ws + off);  off += 16384;
    int*            seg     = (int*)(ws + off);    off += 16384;
    unsigned short* WkT     = (unsigned short*)(ws + off); off += 393216;
    unsigned short* WvT     = (unsigned short*)(ws + off); off += 393216;
    unsigned short* WqT     = (unsigned short*)(ws + off); off += 262144;
    unsigned short* WgT     = (unsigned short*)(ws + off); off += 262144;
    unsigned short* WbackT  = (unsigned short*)(ws + off); off += 262144;
    unsigned short* k_blk   = (unsigned short*)(ws + off); off += 4*MB;
    unsigned short* vT_bf   = (unsigned short*)(ws + off); off += 4*MB;
    unsigned short* q_bf    = (unsigned short*)(ws + off); off += 2*MB;
    float*          gate_ws = (float*)(ws + off); off += 4*MB;
    unsigned short* part_O  = (unsigned short*)(ws + off); off += 16*MB;
    float2*         part_ml = (float2*)(ws + off); off += 1*MB;

    float* out        = (float*)d_out;
    float* out_logits = out + (size_t)NND * IFZ;

    hipLaunchKernelGGL(prep_kernel, dim3(193), dim3(256), 0, stream,
                       Wk, Wv, Wq, Wg, Wback, mraw, braw,
                       WkT, WvT, WqT, WgT, WbackT, mask_f, seg);
    hipLaunchKernelGGL(proj_mfma, dim3(512), dim3(256), 0, stream,
                       emb, x, WkT, WvT, WqT, WgT, bg, k_blk, vT_bf, q_bf, gate_ws);
    hipLaunchKernelGGL(attn_kernel, dim3(BBATCH * ABLK * 16), dim3(256), 0, stream,
                       k_blk, vT_bf, q_bf, mask_f, seg, part_O, part_ml, out_logits);
    hipLaunchKernelGGL(back_ln_fused, dim3(NND / 8), dim3(256), 0, stream,
                       part_O, part_ml, gate_ws, WbackT, x, bback, gamma, beta, out);
}

// Round 8
// 181.059 us; speedup vs baseline: 3.4426x; 1.0317x over previous
//
#include <hip/hip_runtime.h>
#include <hip/hip_bf16.h>

#define NND 2048
#define BBATCH 4
#define SS 1024
#define SFZ 384
#define IFZ 256
#define HH 8
#define AA 64
#define HA 512
#define ABLK 12   // 64-node x-blocks per batch (768-node capacity, 13 sigma)
#define NGRP 4    // 16-node groups per x-block
#define NSPL 8    // S-splits in attention
#define ATTN_BLKS (BBATCH * ABLK * 16)   // 768 attention blocks
#define LOGIT_BLKS (BBATCH * ABLK * 2)   // 96 logits blocks appended

typedef __attribute__((ext_vector_type(8))) short bf16x8;
typedef __attribute__((ext_vector_type(4))) float f32x4;
typedef __attribute__((ext_vector_type(2))) unsigned int u32x2;

__device__ __forceinline__ unsigned short f2bf(float f) {
    union { float f; unsigned u; } a; a.f = f;
    unsigned r = a.u + 0x7fffu + ((a.u >> 16) & 1u);
    return (unsigned short)(r >> 16);
}
__device__ __forceinline__ float bf2f(unsigned short u) {
    return __uint_as_float((unsigned)u << 16);
}

__device__ __forceinline__ bf16x8 cvt8(const float* __restrict__ p) {
    const float4 f0 = *(const float4*)p;
    const float4 f1 = *(const float4*)(p + 4);
    bf16x8 o;
    o[0] = (short)f2bf(f0.x); o[1] = (short)f2bf(f0.y);
    o[2] = (short)f2bf(f0.z); o[3] = (short)f2bf(f0.w);
    o[4] = (short)f2bf(f1.x); o[5] = (short)f2bf(f1.y);
    o[6] = (short)f2bf(f1.z); o[7] = (short)f2bf(f1.w);
    return o;
}

// --- forced-issue async loads (asm volatile preserves issue order) ---
__device__ __forceinline__ bf16x8 gld16(const unsigned short* p) {
    bf16x8 r;
    asm volatile("global_load_dwordx4 %0, %1, off" : "=&v"(r) : "v"(p));
    return r;
}
__device__ __forceinline__ f32x4 gldf4(const float* p) {
    f32x4 r;
    asm volatile("global_load_dwordx4 %0, %1, off" : "=&v"(r) : "v"(p));
    return r;
}
__device__ __forceinline__ u32x2 gld8(const unsigned short* p) {
    u32x2 r;
    asm volatile("global_load_dwordx2 %0, %1, off" : "=&v"(r) : "v"(p));
    return r;
}
#define VMWAIT0() do { \
    asm volatile("s_waitcnt vmcnt(0)" ::: "memory"); \
    __builtin_amdgcn_sched_barrier(0); \
} while (0)

// ---------------------------------------------------------------------------
// Kernel P: prep. Blocks 0..191: weight transposes fp32->bf16.
// Block 192: detect mask/batch dtype -> mask_f, seg.
// ---------------------------------------------------------------------------
__device__ __forceinline__ void tile_transpose(
    const float* __restrict__ src, unsigned short* __restrict__ dst,
    int K, int N, int kt, int nt, int t)
{
    __shared__ unsigned short tile[64][65];
    const int k0 = kt * 64, n0 = nt * 64;
    const int tr = t >> 6, tc = t & 63;
    #pragma unroll
    for (int r = 0; r < 16; ++r)
        tile[tr + r*4][tc] = f2bf(src[(size_t)(k0 + tr + r*4) * N + n0 + tc]);
    __syncthreads();
    #pragma unroll
    for (int r = 0; r < 16; ++r)
        dst[(size_t)(n0 + tr + r*4) * K + k0 + tc] = tile[tc][tr + r*4];
}

__global__ __launch_bounds__(256) void prep_kernel(
    const float* __restrict__ Wk, const float* __restrict__ Wv,
    const float* __restrict__ Wq, const float* __restrict__ Wg,
    const float* __restrict__ Wback,
    const void* __restrict__ mask_raw, const void* __restrict__ batch_raw,
    unsigned short* __restrict__ WkT, unsigned short* __restrict__ WvT,
    unsigned short* __restrict__ WqT, unsigned short* __restrict__ WgT,
    unsigned short* __restrict__ WbackT,
    float* __restrict__ mask_f, int* __restrict__ seg)
{
    const int bx = blockIdx.x, t = threadIdx.x;
    if (bx < 48)  { tile_transpose(Wk, WkT, SFZ, HA, bx/8, bx%8, t); return; }
    if (bx < 96)  { const int i = bx-48;  tile_transpose(Wv, WvT, SFZ, HA, i/8, i%8, t); return; }
    if (bx < 128) { const int i = bx-96;  tile_transpose(Wq, WqT, IFZ, HA, i/8, i%8, t); return; }
    if (bx < 160) { const int i = bx-128; tile_transpose(Wg, WgT, IFZ, HA, i/8, i%8, t); return; }
    if (bx < 192) { const int i = bx-160; tile_transpose(Wback, WbackT, HA, IFZ, i/4, i%4, t); return; }
    __shared__ int fl[4];
    __shared__ int fb;
    __shared__ int cnt[4];
    if (t < 4) { fl[t] = 0; cnt[t] = 0; }
    if (t == 0) fb = 0;
    __syncthreads();
    const unsigned char*  mb = (const unsigned char*)mask_raw;
    const unsigned short* mh = (const unsigned short*)mask_raw;
    const unsigned int*   mw = (const unsigned int*)mask_raw;
    int f0 = 0, f1 = 0, f2 = 0, f3 = 0;
    for (int i = t; i < 2048; i += 256) {
        unsigned short h = mh[i];
        if (h == 0x3f80u) f0 = 1;
        if ((i & 1) == 0 && h != 0) f1 = 1;
    }
    for (int i = t; i < 4096; i += 256)
        if ((i & 3) != 0 && mb[i] != 0) f2 = 1;
    for (int i = t; i < 1024; i += 256)
        if ((i & 1) != 0 && mw[i] != 0) f3 = 1;
    const int* bw = (const int*)batch_raw;
    int f4 = 0;
    for (int i = t + 1; i < 2048; i += 256)
        if (bw[i] < bw[i-1]) f4 = 1;
    if (f0) atomicOr(&fl[0], 1);
    if (f1) atomicOr(&fl[1], 1);
    if (f2) atomicOr(&fl[2], 1);
    if (f3) atomicOr(&fl[3], 1);
    if (f4) atomicOr(&fb, 1);
    __syncthreads();
    int mode;
    if (fl[0])      mode = fl[1] ? 1 : 0;
    else if (fl[2]) mode = 2;
    else if (fl[3]) mode = 3;
    else            mode = 4;
    for (int s = t; s < BBATCH*SS; s += 256) {
        int m;
        switch (mode) {
            case 0:  m = (mw[s]   != 0); break;
            case 1:  m = (mh[s]   != 0); break;
            case 2:  m = (mb[s]   != 0); break;
            case 3:  m = (mw[s]   != 0); break;
            default: m = (mw[2*s] != 0); break;
        }
        mask_f[s] = m ? 1.0f : 0.0f;
    }
    const int b64 = fb;
    for (int i = t; i < NND; i += 256) {
        const int bv = (b64 ? bw[2*i] : bw[i]) & 3;
        atomicAdd(&cnt[bv], 1);
    }
    __syncthreads();
    if (t == 0) {
        int s = 0;
        for (int b = 0; b < 4; ++b) { seg[2*b] = s; s += cnt[b]; seg[2*b+1] = s; }
    }
}

// ---------------------------------------------------------------------------
// Kernel 1: fused MFMA projections (merged k+v / q+gate, R4 form).
// ---------------------------------------------------------------------------
__global__ __launch_bounds__(256, 2) void proj_mfma(
    const float* __restrict__ emb, const float* __restrict__ x,
    const unsigned short* __restrict__ WkT, const unsigned short* __restrict__ WvT,
    const unsigned short* __restrict__ WqT, const unsigned short* __restrict__ WgT,
    const float* __restrict__ bg,
    unsigned short* __restrict__ k_blk, unsigned short* __restrict__ vT_bf,
    unsigned short* __restrict__ q_bf, float* __restrict__ gate_ws)
{
    __shared__ unsigned short v_l[16][520];   // 16.6 KB
    const int t = threadIdx.x, w = t >> 6, lane = t & 63;
    const int m16 = lane & 15, quad = lane >> 4;
    const int bx = blockIdx.x;
    if (bx < 256) {
        const int r0 = bx * 16;
        const int b = r0 >> 10, srow = r0 & (SS - 1);
        const float* ap = emb + (size_t)(r0 + m16) * SFZ + quad * 8;
        bf16x8 af[12];
        #pragma unroll
        for (int j = 0; j < 12; ++j) af[j] = cvt8(ap + j * 32);
        #pragma unroll
        for (int tensor = 0; tensor < 2; ++tensor) {
            const unsigned short* Wt = tensor ? WvT : WkT;
            #pragma unroll
            for (int g = 0; g < 2; ++g) {
                const int n0g = w * 128 + g * 64;
                const unsigned short* bp0 = Wt + (size_t)(n0g +  0 + m16) * SFZ + quad * 8;
                const unsigned short* bp1 = Wt + (size_t)(n0g + 16 + m16) * SFZ + quad * 8;
                const unsigned short* bp2 = Wt + (size_t)(n0g + 32 + m16) * SFZ + quad * 8;
                const unsigned short* bp3 = Wt + (size_t)(n0g + 48 + m16) * SFZ + quad * 8;
                f32x4 a0 = (f32x4){0.f, 0.f, 0.f, 0.f};
                f32x4 a1 = a0, a2 = a0, a3 = a0;
                bf16x8 wb[24];
                #pragma unroll
                for (int j = 0; j < 6; ++j) {
                    wb[j*4+0] = gld16(bp0 + j * 32);
                    wb[j*4+1] = gld16(bp1 + j * 32);
                    wb[j*4+2] = gld16(bp2 + j * 32);
                    wb[j*4+3] = gld16(bp3 + j * 32);
                }
                VMWAIT0();
                #pragma unroll
                for (int j = 0; j < 6; ++j) {
                    a0 = __builtin_amdgcn_mfma_f32_16x16x32_bf16(af[j], wb[j*4+0], a0, 0, 0, 0);
                    a1 = __builtin_amdgcn_mfma_f32_16x16x32_bf16(af[j], wb[j*4+1], a1, 0, 0, 0);
                    a2 = __builtin_amdgcn_mfma_f32_16x16x32_bf16(af[j], wb[j*4+2], a2, 0, 0, 0);
                    a3 = __builtin_amdgcn_mfma_f32_16x16x32_bf16(af[j], wb[j*4+3], a3, 0, 0, 0);
                }
                #pragma unroll
                for (int j = 6; j < 12; ++j) {
                    wb[(j-6)*4+0] = gld16(bp0 + j * 32);
                    wb[(j-6)*4+1] = gld16(bp1 + j * 32);
                    wb[(j-6)*4+2] = gld16(bp2 + j * 32);
                    wb[(j-6)*4+3] = gld16(bp3 + j * 32);
                }
                VMWAIT0();
                #pragma unroll
                for (int j = 6; j < 12; ++j) {
                    a0 = __builtin_amdgcn_mfma_f32_16x16x32_bf16(af[j], wb[(j-6)*4+0], a0, 0, 0, 0);
                    a1 = __builtin_amdgcn_mfma_f32_16x16x32_bf16(af[j], wb[(j-6)*4+1], a1, 0, 0, 0);
                    a2 = __builtin_amdgcn_mfma_f32_16x16x32_bf16(af[j], wb[(j-6)*4+2], a2, 0, 0, 0);
                    a3 = __builtin_amdgcn_mfma_f32_16x16x32_bf16(af[j], wb[(j-6)*4+3], a3, 0, 0, 0);
                }
                f32x4 dd[4] = {a0, a1, a2, a3};
                if (tensor == 0) {
                    #pragma unroll
                    for (int u = 0; u < 4; ++u) {
                        const int n0 = n0g + u * 16;
                        const int head = n0 >> 6, coff = (n0 & 63) + m16;
                        unsigned short* kb = k_blk + (((size_t)(b * HH + head)) * SS) * 64 + coff;
                        #pragma unroll
                        for (int r = 0; r < 4; ++r)
                            kb[(size_t)(srow + quad * 4 + r) * 64] = f2bf(dd[u][r]);
                    }
                } else {
                    #pragma unroll
                    for (int u = 0; u < 4; ++u) {
                        const int c0 = n0g + u * 16 + m16;
                        #pragma unroll
                        for (int r = 0; r < 4; ++r)
                            v_l[quad * 4 + r][c0] = f2bf(dd[u][r]);
                    }
                }
            }
        }
        __syncthreads();
        for (int c = t; c < HA; c += 256) {
            unsigned short tmp[16];
            #pragma unroll
            for (int s = 0; s < 16; ++s) tmp[s] = v_l[s][c];
            unsigned short* dst = vT_bf + ((size_t)b * HA + c) * SS + srow;
            *(uint4*)dst       = ((const uint4*)tmp)[0];
            *(uint4*)(dst + 8) = ((const uint4*)tmp)[1];
        }
    } else {
        const int i = bx - 256;
        const int r0 = (i >> 1) * 16;
        const int half = i & 1;
        const float* ap = x + (size_t)(r0 + m16) * IFZ + quad * 8;
        bf16x8 af[8];
        #pragma unroll
        for (int j = 0; j < 8; ++j) af[j] = cvt8(ap + j * 32);
        const int n0b = half * 256 + w * 64;
        #pragma unroll
        for (int tensor = 0; tensor < 2; ++tensor) {
            const unsigned short* Wt = tensor ? WgT : WqT;
            const unsigned short* bp0 = Wt + (size_t)(n0b +  0 + m16) * IFZ + quad * 8;
            const unsigned short* bp1 = Wt + (size_t)(n0b + 16 + m16) * IFZ + quad * 8;
            const unsigned short* bp2 = Wt + (size_t)(n0b + 32 + m16) * IFZ + quad * 8;
            const unsigned short* bp3 = Wt + (size_t)(n0b + 48 + m16) * IFZ + quad * 8;
            bf16x8 wb[32];
            #pragma unroll
            for (int j = 0; j < 8; ++j) {
                wb[j*4+0] = gld16(bp0 + j * 32);
                wb[j*4+1] = gld16(bp1 + j * 32);
                wb[j*4+2] = gld16(bp2 + j * 32);
                wb[j*4+3] = gld16(bp3 + j * 32);
            }
            VMWAIT0();
            f32x4 a0 = (f32x4){0.f, 0.f, 0.f, 0.f};
            f32x4 a1 = a0, a2 = a0, a3 = a0;
            #pragma unroll
            for (int j = 0; j < 8; ++j) {
                a0 = __builtin_amdgcn_mfma_f32_16x16x32_bf16(af[j], wb[j*4+0], a0, 0, 0, 0);
                a1 = __builtin_amdgcn_mfma_f32_16x16x32_bf16(af[j], wb[j*4+1], a1, 0, 0, 0);
                a2 = __builtin_amdgcn_mfma_f32_16x16x32_bf16(af[j], wb[j*4+2], a2, 0, 0, 0);
                a3 = __builtin_amdgcn_mfma_f32_16x16x32_bf16(af[j], wb[j*4+3], a3, 0, 0, 0);
            }
            f32x4 dd[4] = {a0, a1, a2, a3};
            if (tensor == 0) {
                #pragma unroll
                for (int u = 0; u < 4; ++u) {
                    const int n0 = n0b + u * 16;
                    #pragma unroll
                    for (int r = 0; r < 4; ++r)
                        q_bf[(size_t)(r0 + quad * 4 + r) * HA + n0 + m16] = f2bf(dd[u][r]);
                }
            } else {
                #pragma unroll
                for (int u = 0; u < 4; ++u) {
                    const int n0 = n0b + u * 16;
                    const float bgv = bg[n0 + m16];
                    #pragma unroll
                    for (int r = 0; r < 4; ++r)
                        gate_ws[(size_t)(r0 + quad * 4 + r) * HA + n0 + m16] =
                            1.f / (1.f + __expf(-(dd[u][r] + bgv)));
                }
            }
        }
    }
}

// ---------------------------------------------------------------------------
// Kernel 3: flash attention (barrier-free) + appended logits blocks.
// Blocks [0,768): attention. Per-wave fully independent: swapped-QK^T
// lane-local softmax, K in regs across 4 node-groups, NO __syncthreads
// anywhere (logits evicted). LDS 17.4 KB (was 34.3).
// Blocks [768,864): logits = (q_h0 K_h0^T + q_h1 K_h1^T)/8 recomputed
// directly (2/16ths of QK work), stored raw, no softmax coupling.
// ---------------------------------------------------------------------------
__global__ __launch_bounds__(256, 2) void attn_kernel(
    const unsigned short* __restrict__ k_blk, const unsigned short* __restrict__ vT_bf,
    const unsigned short* __restrict__ q_bf, const float* __restrict__ mask_f,
    const int* __restrict__ seg, unsigned short* __restrict__ part_O,
    float2* __restrict__ part_ml, float* __restrict__ out_logits)
{
    __shared__ unsigned short P_lds[4][16][136];   // 17.4 KB
    const int bid = blockIdx.x;
    const int t = threadIdx.x;
    const int w = t >> 6, lane = t & 63;
    const int m16 = lane & 15, quad = lane >> 4;

    if (bid >= ATTN_BLKS) {
        // ================== logits role ==================
        const int lid = bid - ATTN_BLKS;          // [0,96)
        const int b = lid / 24;
        const int rem = lid % 24;
        const int xblk = rem >> 1;                // [0,12)
        const int spair = rem & 1;
        const int s0 = (spair * 4 + w) * 128;
        const int nbase = seg[2*b] + xblk * 64;
        const int nend  = seg[2*b + 1];
        if (nbase >= nend) return;
        const unsigned short* kb0 = k_blk + ((size_t)(b * HH + 0)) * SS * 64;
        const unsigned short* kb1 = k_blk + ((size_t)(b * HH + 1)) * SS * 64;
        bf16x8 k0[16], k1[16];
        #pragma unroll
        for (int st = 0; st < 8; ++st) {
            const unsigned short* kp0 = kb0 + (size_t)(s0 + st * 16 + m16) * 64 + quad * 8;
            const unsigned short* kp1 = kb1 + (size_t)(s0 + st * 16 + m16) * 64 + quad * 8;
            k0[2*st]   = gld16(kp0);
            k0[2*st+1] = gld16(kp0 + 32);
            k1[2*st]   = gld16(kp1);
            k1[2*st+1] = gld16(kp1 + 32);
        }
        VMWAIT0();
        for (int g = 0; g < NGRP; ++g) {
            const int n0g = nbase + g * 16;
            if (n0g >= nend) break;
            const int nvalid = min(16, nend - n0g);
            int nq = n0g + m16; if (nq >= nend) nq = nend - 1;
            const unsigned short* qp = q_bf + (size_t)nq * HA + quad * 8;
            const bf16x8 q0a = gld16(qp);
            const bf16x8 q0b = gld16(qp + 32);
            const bf16x8 q1a = gld16(qp + 64);
            const bf16x8 q1b = gld16(qp + 96);
            VMWAIT0();
            #pragma unroll
            for (int st = 0; st < 8; ++st) {
                f32x4 acc = (f32x4){0.f, 0.f, 0.f, 0.f};
                acc = __builtin_amdgcn_mfma_f32_16x16x32_bf16(q0a, k0[2*st],   acc, 0, 0, 0);
                acc = __builtin_amdgcn_mfma_f32_16x16x32_bf16(q0b, k0[2*st+1], acc, 0, 0, 0);
                acc = __builtin_amdgcn_mfma_f32_16x16x32_bf16(q1a, k1[2*st],   acc, 0, 0, 0);
                acc = __builtin_amdgcn_mfma_f32_16x16x32_bf16(q1b, k1[2*st+1], acc, 0, 0, 0);
                #pragma unroll
                for (int r = 0; r < 4; ++r) {
                    const int row = quad * 4 + r;
                    if (row < nvalid)
                        out_logits[(size_t)(n0g + row) * SS + s0 + st * 16 + m16] =
                            acc[r] * 0.125f;
                }
            }
        }
        return;
    }

    // ================== attention role (barrier-free) ==================
    const int xcd = bid & 7;
    const int b   = xcd >> 1;
    const int idx = (bid >> 3) * 2 + (xcd & 1);   // [0,192)
    const int z    = idx & 15;
    const int xblk = idx >> 4;                    // [0,12)
    const int hz    = z >> 3;
    const int split = z & 7;
    const int nbase = seg[2*b] + xblk * (16 * NGRP);
    const int nend  = seg[2*b + 1];
    if (nbase >= nend) return;

    const int h = hz * 4 + w;
    const int s0 = split * 128;

    const unsigned short* kb = k_blk + ((size_t)(b * HH + h)) * SS * 64;
    const unsigned short* vb = vT_bf + ((size_t)b * HA + h * AA) * SS;
    const unsigned short* qbase = q_bf + (size_t)h * AA + quad * 8;
    unsigned short (*Pw)[136] = P_lds[w];

    // ---- prologue burst: K(16) + mask(8) + q0(2) ----
    bf16x8 kf[16];
    #pragma unroll
    for (int st = 0; st < 8; ++st) {
        const unsigned short* kp = kb + (size_t)(s0 + st * 16 + m16) * 64 + quad * 8;
        kf[2*st]   = gld16(kp);
        kf[2*st+1] = gld16(kp + 32);
    }
    f32x4 mkv[8];
    #pragma unroll
    for (int st = 0; st < 8; ++st)
        mkv[st] = gldf4(mask_f + b * SS + s0 + st * 16 + quad * 4);
    int nq0 = nbase + m16; if (nq0 >= nend) nq0 = nend - 1;
    bf16x8 qc0 = gld16(qbase + (size_t)nq0 * HA);
    bf16x8 qc1 = gld16(qbase + (size_t)nq0 * HA + 32);
    VMWAIT0();
    // ---- per-lane mask bitmask: bit (st*4+r) <-> s = st*16 + quad*4 + r ----
    unsigned bm = 0u;
    #pragma unroll
    for (int st = 0; st < 8; ++st)
        #pragma unroll
        for (int r = 0; r < 4; ++r)
            if (mkv[st][r] > 0.5f) bm |= (1u << (st * 4 + r));

    bf16x8 qn0 = qc0, qn1 = qc1;
    for (int g = 0; g < NGRP; ++g) {
        const int n0g = nbase + g * 16;
        if (n0g >= nend) break;                     // block-uniform
        const int nvalid = min(16, nend - n0g);

        // ---- QK^T swapped: C[row=s(st*16+quad*4+r)][col=node(m16)] ----
        f32x4 d[8];
        #pragma unroll
        for (int st = 0; st < 8; ++st) {
            f32x4 acc = (f32x4){0.f, 0.f, 0.f, 0.f};
            acc = __builtin_amdgcn_mfma_f32_16x16x32_bf16(kf[2*st],   qc0, acc, 0, 0, 0);
            acc = __builtin_amdgcn_mfma_f32_16x16x32_bf16(kf[2*st+1], qc1, acc, 0, 0, 0);
            #pragma unroll
            for (int r = 0; r < 4; ++r) acc[r] *= 0.125f;
            d[st] = acc;
        }
        // ---- issue V burst + next-q; softmax hides their latency ----
        bf16x8 vf[16];
        #pragma unroll
        for (int sub = 0; sub < 4; ++sub) {
            const unsigned short* vp0 = vb + (size_t)m16 * SS + s0 + sub * 32 + quad * 8;
            #pragma unroll
            for (int a = 0; a < 4; ++a)
                vf[sub*4+a] = gld16(vp0 + (size_t)(a * 16) * SS);
        }
        if (g + 1 < NGRP && nbase + (g + 1) * 16 < nend) {
            int nqn = nbase + (g + 1) * 16 + m16; if (nqn >= nend) nqn = nend - 1;
            qn0 = gld16(qbase + (size_t)nqn * HA);
            qn1 = gld16(qbase + (size_t)nqn * HA + 32);
        }
        __builtin_amdgcn_sched_barrier(0);

        // ---- lane-local masked softmax (node = m16, per lane) ----
        #pragma unroll
        for (int st = 0; st < 8; ++st)
            #pragma unroll
            for (int r = 0; r < 4; ++r)
                if (!((bm >> (st * 4 + r)) & 1u)) d[st][r] = -3.0e38f;
        float mx = -3.0e38f;
        #pragma unroll
        for (int st = 0; st < 8; ++st) {
            float a = fmaxf(fmaxf(d[st][0], d[st][1]), fmaxf(d[st][2], d[st][3]));
            mx = fmaxf(mx, a);
        }
        mx = fmaxf(mx, __shfl_xor(mx, 16));
        mx = fmaxf(mx, __shfl_xor(mx, 32));
        mx = fmaxf(mx, -1.0e30f);      // all-masked rows -> exp underflow -> l=0
        float cs = 0.f;
        #pragma unroll
        for (int st = 0; st < 8; ++st)
            #pragma unroll
            for (int r = 0; r < 4; ++r) {
                const float e = __expf(d[st][r] - mx);
                d[st][r] = e;
                cs += e;
            }
        cs += __shfl_xor(cs, 16);
        cs += __shfl_xor(cs, 32);
        // ---- P -> LDS: lane owns node m16, 4 contiguous bf16 per st ----
        #pragma unroll
        for (int st = 0; st < 8; ++st) {
            ushort4 pk;
            pk.x = f2bf(d[st][0]); pk.y = f2bf(d[st][1]);
            pk.z = f2bf(d[st][2]); pk.w = f2bf(d[st][3]);
            *(ushort4*)&Pw[m16][st * 16 + quad * 4] = pk;
        }
        bf16x8 pa[4];
        #pragma unroll
        for (int sub = 0; sub < 4; ++sub)
            pa[sub] = *(const bf16x8*)&Pw[m16][sub * 32 + quad * 8];
        // ---- wait V (stores from prior group long retired); PV ----
        VMWAIT0();
        f32x4 facc[4];
        #pragma unroll
        for (int a = 0; a < 4; ++a) facc[a] = (f32x4){0.f, 0.f, 0.f, 0.f};
        #pragma unroll
        for (int sub = 0; sub < 4; ++sub) {
            #pragma unroll
            for (int a = 0; a < 4; ++a)
                facc[a] = __builtin_amdgcn_mfma_f32_16x16x32_bf16(pa[sub], vf[sub*4+a], facc[a], 0, 0, 0);
        }
        // ---- epilogue: partial O (C row=node) + per-node (m,l) ----
        unsigned short* po = part_O + (size_t)split * NND * HA;
        #pragma unroll
        for (int a = 0; a < 4; ++a)
            #pragma unroll
            for (int r = 0; r < 4; ++r) {
                const int row = quad * 4 + r;
                if (row < nvalid)
                    po[(size_t)(n0g + row) * HA + h * AA + a * 16 + m16] = f2bf(facc[a][r]);
            }
        if (quad == 0 && m16 < nvalid)
            part_ml[(size_t)split * NND * HH + (size_t)(n0g + m16) * HH + h] =
                make_float2(mx, cs);
        qc0 = qn0; qc1 = qn1;
    }
}

// ---------------------------------------------------------------------------
// Kernel 4: fused combine(8 splits) + gate mul + Wback MFMA + residual + LN.
// ---------------------------------------------------------------------------
__global__ __launch_bounds__(256, 2) void back_ln_fused(
    const unsigned short* __restrict__ part_O, const float2* __restrict__ part_ml,
    const float* __restrict__ gate_ws, const unsigned short* __restrict__ WbackT,
    const float* __restrict__ x, const float* __restrict__ bback,
    const float* __restrict__ gamma, const float* __restrict__ beta,
    float* __restrict__ out)
{
    __shared__ float coef[NSPL][8][8];
    __shared__ unsigned short gf_l[8][520];
    __shared__ float nl[8][260];
    const int t = threadIdx.x, w = t >> 6, lane = t & 63;
    const int m16 = lane & 15, quad = lane >> 4;
    const int r0 = blockIdx.x * 8;
    if (t < 64) {
        const int row = t >> 3, h = t & 7, n = r0 + row;
        float2 ml[NSPL];
        #pragma unroll
        for (int s = 0; s < NSPL; ++s)
            ml[s] = part_ml[(size_t)s * NND * HH + (size_t)n * HH + h];
        float M = -3.0e38f;
        #pragma unroll
        for (int s = 0; s < NSPL; ++s) M = fmaxf(M, ml[s].x);
        float L = 0.f;
        float e[NSPL];
        #pragma unroll
        for (int s = 0; s < NSPL; ++s) { e[s] = __expf(ml[s].x - M); L += ml[s].y * e[s]; }
        const float invL = 1.f / (L + 1e-9f);
        #pragma unroll
        for (int s = 0; s < NSPL; ++s) coef[s][row][h] = e[s] * invL;
    }
    u32x2 pvv[4][NSPL];
    f32x4 gv[4];
    #pragma unroll
    for (int it = 0; it < 4; ++it) {
        const int i = (t + it * 256) * 4;
        const int row = i >> 9, c = i & (HA - 1);
        const int n = r0 + row;
        #pragma unroll
        for (int s = 0; s < NSPL; ++s)
            pvv[it][s] = gld8(&part_O[(size_t)s * NND * HA + (size_t)n * HA + c]);
        gv[it] = gldf4(&gate_ws[(size_t)n * HA + c]);
    }
    __syncthreads();   // coef ready
    VMWAIT0();
    #pragma unroll
    for (int it = 0; it < 4; ++it) {
        const int i = (t + it * 256) * 4;
        const int row = i >> 9, c = i & (HA - 1), h = c >> 6;
        float4 o = make_float4(0.f, 0.f, 0.f, 0.f);
        #pragma unroll
        for (int s = 0; s < NSPL; ++s) {
            const float cf = coef[s][row][h];
            o.x = fmaf(bf2f((unsigned short)(pvv[it][s][0] & 0xffffu)), cf, o.x);
            o.y = fmaf(bf2f((unsigned short)(pvv[it][s][0] >> 16)),     cf, o.y);
            o.z = fmaf(bf2f((unsigned short)(pvv[it][s][1] & 0xffffu)), cf, o.z);
            o.w = fmaf(bf2f((unsigned short)(pvv[it][s][1] >> 16)),     cf, o.w);
        }
        ushort4 ob;
        ob.x = f2bf(gv[it][0] * o.x); ob.y = f2bf(gv[it][1] * o.y);
        ob.z = f2bf(gv[it][2] * o.z); ob.w = f2bf(gv[it][3] * o.w);
        *(ushort4*)&gf_l[row][c] = ob;
    }
    __syncthreads();
    bf16x8 af[16];
    #pragma unroll
    for (int j = 0; j < 16; ++j)
        af[j] = *(const bf16x8*)&gf_l[m16 & 7][quad * 8 + j * 32];
    const unsigned short* bq0 = WbackT + (size_t)(w * 64 +  0 + m16) * HA + quad * 8;
    const unsigned short* bq1 = WbackT + (size_t)(w * 64 + 16 + m16) * HA + quad * 8;
    const unsigned short* bq2 = WbackT + (size_t)(w * 64 + 32 + m16) * HA + quad * 8;
    const unsigned short* bq3 = WbackT + (size_t)(w * 64 + 48 + m16) * HA + quad * 8;
    f32x4 a0 = (f32x4){0.f, 0.f, 0.f, 0.f};
    f32x4 a1 = a0, a2 = a0, a3 = a0;
    #pragma unroll
    for (int jb = 0; jb < 4; ++jb) {
        bf16x8 wb[16];
        #pragma unroll
        for (int j = 0; j < 4; ++j) {
            wb[j*4+0] = gld16(bq0 + (jb*4 + j) * 32);
            wb[j*4+1] = gld16(bq1 + (jb*4 + j) * 32);
            wb[j*4+2] = gld16(bq2 + (jb*4 + j) * 32);
            wb[j*4+3] = gld16(bq3 + (jb*4 + j) * 32);
        }
        VMWAIT0();
        #pragma unroll
        for (int j = 0; j < 4; ++j) {
            a0 = __builtin_amdgcn_mfma_f32_16x16x32_bf16(af[jb*4+j], wb[j*4+0], a0, 0, 0, 0);
            a1 = __builtin_amdgcn_mfma_f32_16x16x32_bf16(af[jb*4+j], wb[j*4+1], a1, 0, 0, 0);
            a2 = __builtin_amdgcn_mfma_f32_16x16x32_bf16(af[jb*4+j], wb[j*4+2], a2, 0, 0, 0);
            a3 = __builtin_amdgcn_mfma_f32_16x16x32_bf16(af[jb*4+j], wb[j*4+3], a3, 0, 0, 0);
        }
    }
    {
        f32x4 dd[4] = {a0, a1, a2, a3};
        #pragma unroll
        for (int u = 0; u < 4; ++u) {
            const int n0 = w * 64 + u * 16;
            const float bb = bback[n0 + m16];
            #pragma unroll
            for (int r = 0; r < 4; ++r) {
                const int rr = quad * 4 + r;
                if (rr < 8) nl[rr][n0 + m16] = dd[u][r] + bb;
            }
        }
    }
    __syncthreads();
    const int row = t >> 5, li = t & 31;
    const float* xr = x + (size_t)(r0 + row) * IFZ;
    float yv[8];
    float s1 = 0.f, s2 = 0.f;
    #pragma unroll
    for (int j = 0; j < 8; ++j) {
        const int c = li + j * 32;
        const float v = fmaf(1.41421356237309515f, xr[c], nl[row][c]);
        yv[j] = v; s1 += v; s2 += v * v;
    }
    #pragma unroll
    for (int off = 16; off >= 1; off >>= 1) {
        s1 += __shfl_xor(s1, off);
        s2 += __shfl_xor(s2, off);
    }
    const float mu  = s1 * (1.f / IFZ);
    const float var = s2 * (1.f / IFZ) - mu * mu;
    const float rv  = rsqrtf(var + 1e-5f);
    float* orow = out + (size_t)(r0 + row) * IFZ;
    #pragma unroll
    for (int j = 0; j < 8; ++j) {
        const int c = li + j * 32;
        orow[c] = (yv[j] - mu) * rv * gamma[c] + beta[c];
    }
}

extern "C" void kernel_launch(void* const* d_in, const int* in_sizes, int n_in,
                              void* d_out, int out_size, void* d_ws, size_t ws_size,
                              hipStream_t stream) {
    const float* x     = (const float*)d_in[0];
    const float* emb   = (const float*)d_in[1];
    const void*  mraw  = d_in[2];
    const void*  braw  = d_in[3];
    const float* Wq    = (const float*)d_in[4];
    const float* Wk    = (const float*)d_in[5];
    const float* Wv    = (const float*)d_in[6];
    const float* Wg    = (const float*)d_in[7];
    const float* bg    = (const float*)d_in[8];
    const float* Wback = (const float*)d_in[9];
    const float* bback = (const float*)d_in[10];
    const float* gamma = (const float*)d_in[11];
    const float* beta  = (const float*)d_in[12];

    char* ws = (char*)d_ws;
    const size_t MB = 1048576;
    size_t off = 0;
    float*          mask_f  = (float*)(ws + off);  off += 16384;
    int*            seg     = (int*)(ws + off);    off += 16384;
    unsigned short* WkT     = (unsigned short*)(ws + off); off += 393216;
    unsigned short* WvT     = (unsigned short*)(ws + off); off += 393216;
    unsigned short* WqT     = (unsigned short*)(ws + off); off += 262144;
    unsigned short* WgT     = (unsigned short*)(ws + off); off += 262144;
    unsigned short* WbackT  = (unsigned short*)(ws + off); off += 262144;
    unsigned short* k_blk   = (unsigned short*)(ws + off); off += 4*MB;
    unsigned short* vT_bf   = (unsigned short*)(ws + off); off += 4*MB;
    unsigned short* q_bf    = (unsigned short*)(ws + off); off += 2*MB;
    float*          gate_ws = (float*)(ws + off); off += 4*MB;
    unsigned short* part_O  = (unsigned short*)(ws + off); off += 16*MB;
    float2*         part_ml = (float2*)(ws + off); off += 1*MB;

    float* out        = (float*)d_out;
    float* out_logits = out + (size_t)NND * IFZ;

    hipLaunchKernelGGL(prep_kernel, dim3(193), dim3(256), 0, stream,
                       Wk, Wv, Wq, Wg, Wback, mraw, braw,
                       WkT, WvT, WqT, WgT, WbackT, mask_f, seg);
    hipLaunchKernelGGL(proj_mfma, dim3(512), dim3(256), 0, stream,
                       emb, x, WkT, WvT, WqT, WgT, bg, k_blk, vT_bf, q_bf, gate_ws);
    hipLaunchKernelGGL(attn_kernel, dim3(ATTN_BLKS + LOGIT_BLKS), dim3(256), 0, stream,
                       k_blk, vT_bf, q_bf, mask_f, seg, part_O, part_ml, out_logits);
    hipLaunchKernelGGL(back_ln_fused, dim3(NND / 8), dim3(256), 0, stream,
                       part_O, part_ml, gate_ws, WbackT, x, bback, gamma, beta, out);
}